// Round 1
// baseline (1588.195 us; speedup 1.0000x reference)
//
#include <hip/hip_runtime.h>
#include <hip/hip_bf16.h>

// GAT 2-layer, fp32. N=100000, IN=128, L1: H=4,C=32 (HC=128), L2: H=1,C=32.
//
// Pipeline per layer:
//   gemm+att  -> h[N,HC], a_src[N,H], a_dst[N,H]
//   edge_max  -> m[dst,h] via atomicMax on monotonic uint encoding
//   edge_acc  -> den[dst,h] += ex ; acc[dst,ch] += ex * h[src,ch]   (unnormalized)
//   normalize -> acc/(den+eps) + bias (+relu for layer 1)
// Self-loops are implicit: edge ids >= E map to (n,n).

__device__ __forceinline__ unsigned enc_max(float v) {
    unsigned u = __float_as_uint(v);
    return (u & 0x80000000u) ? ~u : (u | 0x80000000u);
}
__device__ __forceinline__ float dec_max(unsigned u) {
    return __uint_as_float((u & 0x80000000u) ? (u ^ 0x80000000u) : ~u);
}
__device__ __forceinline__ float lrelu(float v) { return v >= 0.f ? v : 0.2f * v; }

// ---------------- GEMM1: x[N,128] @ W[128,128] -> h[N,128]; fused a_src/a_dst (H=4,C=32)
__global__ __launch_bounds__(256) void gemm1_att(
    const float* __restrict__ x, const float* __restrict__ W,
    const float* __restrict__ atts, const float* __restrict__ attd,
    float* __restrict__ h, float* __restrict__ as_, float* __restrict__ ad_, int N) {
    __shared__ float xs[64][33];
    __shared__ float ws[32][132];
    const int t = threadIdx.x;
    const int n0 = blockIdx.x * 64;
    const int tcol = t & 31;        // 32 col-groups of 4 cols
    const int trow = t >> 5;        // 8 row-groups of 8 rows
    float acc[8][4];
#pragma unroll
    for (int i = 0; i < 8; i++) { acc[i][0]=0.f; acc[i][1]=0.f; acc[i][2]=0.f; acc[i][3]=0.f; }

    for (int k0 = 0; k0 < 128; k0 += 32) {
        {   // stage x tile 64x32
            int k = t & 31, r0 = t >> 5;
#pragma unroll
            for (int i = 0; i < 8; i++) {
                int r = r0 + i * 8;
                int n = n0 + r;
                xs[r][k] = (n < N) ? x[(size_t)n * 128 + k0 + k] : 0.f;
            }
        }
        {   // stage W tile 32x128
            int c = t & 127, kk = t >> 7;
#pragma unroll
            for (int i = 0; i < 16; i++) {
                int k = kk + i * 2;
                ws[k][c] = W[(k0 + k) * 128 + c];
            }
        }
        __syncthreads();
#pragma unroll
        for (int k = 0; k < 32; k++) {
            float4 wv = *(const float4*)&ws[k][tcol * 4];
#pragma unroll
            for (int i = 0; i < 8; i++) {
                float xv = xs[trow * 8 + i][k];
                acc[i][0] += xv * wv.x; acc[i][1] += xv * wv.y;
                acc[i][2] += xv * wv.z; acc[i][3] += xv * wv.w;
            }
        }
        __syncthreads();
    }

    const int head = tcol >> 3;           // 8 threads per head
    const int cbase = tcol * 4;           // output col base
    const int csub = cbase - head * 32;   // col within head
    float s0 = atts[head * 32 + csub + 0], s1 = atts[head * 32 + csub + 1],
          s2 = atts[head * 32 + csub + 2], s3 = atts[head * 32 + csub + 3];
    float d0 = attd[head * 32 + csub + 0], d1 = attd[head * 32 + csub + 1],
          d2 = attd[head * 32 + csub + 2], d3 = attd[head * 32 + csub + 3];
#pragma unroll
    for (int i = 0; i < 8; i++) {
        int n = n0 + trow * 8 + i;
        if (n < N) {
            float4 hv = make_float4(acc[i][0], acc[i][1], acc[i][2], acc[i][3]);
            *(float4*)&h[(size_t)n * 128 + cbase] = hv;
            float ps = acc[i][0]*s0 + acc[i][1]*s1 + acc[i][2]*s2 + acc[i][3]*s3;
            float pd = acc[i][0]*d0 + acc[i][1]*d1 + acc[i][2]*d2 + acc[i][3]*d3;
            ps += __shfl_xor(ps, 1); pd += __shfl_xor(pd, 1);
            ps += __shfl_xor(ps, 2); pd += __shfl_xor(pd, 2);
            ps += __shfl_xor(ps, 4); pd += __shfl_xor(pd, 4);
            if ((tcol & 7) == 0) { as_[n * 4 + head] = ps; ad_[n * 4 + head] = pd; }
        }
    }
}

// ---------------- GEMM2: h1[N,128] @ W2[128,32] -> h2[N,32]; fused a_src/a_dst (H=1,C=32)
__global__ __launch_bounds__(256) void gemm2_att(
    const float* __restrict__ x, const float* __restrict__ W,
    const float* __restrict__ atts, const float* __restrict__ attd,
    float* __restrict__ h, float* __restrict__ as_, float* __restrict__ ad_, int N) {
    __shared__ float xs[64][33];
    __shared__ float ws[32][33];
    const int t = threadIdx.x;
    const int n0 = blockIdx.x * 64;
    const int tcol = t & 31;   // one col each
    const int trow = t >> 5;   // 8 rows each
    float acc[8];
#pragma unroll
    for (int i = 0; i < 8; i++) acc[i] = 0.f;

    for (int k0 = 0; k0 < 128; k0 += 32) {
        {
            int k = t & 31, r0 = t >> 5;
#pragma unroll
            for (int i = 0; i < 8; i++) {
                int r = r0 + i * 8;
                int n = n0 + r;
                xs[r][k] = (n < N) ? x[(size_t)n * 128 + k0 + k] : 0.f;
            }
        }
        {
            int c = t & 31, kk = t >> 5;
#pragma unroll
            for (int i = 0; i < 4; i++) {
                int k = kk + i * 8;
                ws[k][c] = W[(k0 + k) * 32 + c];
            }
        }
        __syncthreads();
#pragma unroll
        for (int k = 0; k < 32; k++) {
            float wv = ws[k][tcol];
#pragma unroll
            for (int i = 0; i < 8; i++) acc[i] += xs[trow * 8 + i][k] * wv;
        }
        __syncthreads();
    }

    float sa = atts[tcol], da = attd[tcol];
#pragma unroll
    for (int i = 0; i < 8; i++) {
        int n = n0 + trow * 8 + i;
        if (n < N) {
            h[(size_t)n * 32 + tcol] = acc[i];
            float ps = acc[i] * sa;
            float pd = acc[i] * da;
#pragma unroll
            for (int m = 1; m < 32; m <<= 1) { ps += __shfl_xor(ps, m); pd += __shfl_xor(pd, m); }
            if (tcol == 0) { as_[n] = ps; ad_[n] = pd; }
        }
    }
}

// ---------------- edge pass A: segment max per (dst, head)
template <int H>
__global__ __launch_bounds__(256) void edge_max_k(
    const int* __restrict__ ei, int E, int N,
    const float* __restrict__ as_, const float* __restrict__ ad_,
    unsigned* __restrict__ mx) {
    int tid = blockIdx.x * 256 + threadIdx.x;
    int total = (E + N) * H;
    if (tid >= total) return;
    int e = tid / H, hh = tid - e * H;
    int s, d;
    if (e < E) { s = ei[e]; d = ei[E + e]; } else { s = e - E; d = s; }
    float v = lrelu(as_[s * H + hh] + ad_[d * H + hh]);
    atomicMax(&mx[d * H + hh], enc_max(v));
}

// ---------------- edge pass B: den += ex ; acc += ex * h[src]
template <int H, int C>
__global__ __launch_bounds__(256) void edge_acc_k(
    const int* __restrict__ ei, int E, int N,
    const float* __restrict__ as_, const float* __restrict__ ad_,
    const unsigned* __restrict__ mx, const float* __restrict__ hsrc,
    float* __restrict__ den, float* __restrict__ acc) {
    constexpr int HC = H * C;
    long long tid = (long long)blockIdx.x * 256 + threadIdx.x;
    long long total = (long long)(E + N) * HC;
    if (tid >= total) return;
    int e = (int)(tid / HC);
    int ch = (int)(tid - (long long)e * HC);
    int hh = ch / C;
    int s, d;
    if (e < E) { s = ei[e]; d = ei[E + e]; } else { s = e - E; d = s; }
    float v = lrelu(as_[s * H + hh] + ad_[d * H + hh]);
    float m = dec_max(mx[d * H + hh]);
    float ex = __expf(v - m);
    if ((ch & (C - 1)) == 0) atomicAdd(&den[d * H + hh], ex);
    atomicAdd(&acc[(size_t)d * HC + ch], ex * hsrc[(size_t)s * HC + ch]);
}

// ---------------- normalize layer 1 (+bias+relu)
__global__ __launch_bounds__(256) void norm_relu_k(
    const float* __restrict__ acc, const float* __restrict__ den,
    const float* __restrict__ b, float* __restrict__ o, int N) {
    int tid = blockIdx.x * 256 + threadIdx.x;
    if (tid >= N * 128) return;
    int n = tid >> 7, ch = tid & 127, hh = ch >> 5;
    float v = acc[tid] / (den[n * 4 + hh] + 1e-16f) + b[ch];
    o[tid] = v > 0.f ? v : 0.f;
}

// ---------------- normalize layer 2 (+bias), in place on d_out
__global__ __launch_bounds__(256) void norm_out_k(
    const float* __restrict__ den, const float* __restrict__ b,
    float* __restrict__ o, int N) {
    int tid = blockIdx.x * 256 + threadIdx.x;
    if (tid >= N * 32) return;
    int n = tid >> 5, c = tid & 31;
    o[tid] = o[tid] / (den[n] + 1e-16f) + b[c];
}

extern "C" void kernel_launch(void* const* d_in, const int* in_sizes, int n_in,
                              void* d_out, int out_size, void* d_ws, size_t ws_size,
                              hipStream_t stream) {
    const float* x    = (const float*)d_in[0];
    const int*   ei   = (const int*)d_in[1];
    const float* W1   = (const float*)d_in[2];
    const float* as1v = (const float*)d_in[3];
    const float* ad1v = (const float*)d_in[4];
    const float* b1   = (const float*)d_in[5];
    const float* W2   = (const float*)d_in[6];
    const float* as2v = (const float*)d_in[7];
    const float* ad2v = (const float*)d_in[8];
    const float* b2   = (const float*)d_in[9];
    float* out = (float*)d_out;

    const int N = in_sizes[0] / 128;
    const int E = in_sizes[1] / 2;

    // workspace layout (floats)
    float* w = (float*)d_ws;
    size_t o = 0;
    float*    h1   = w + o; o += (size_t)N * 128;
    float*    acc1 = w + o; o += (size_t)N * 128;
    float*    as1  = w + o; o += (size_t)N * 4;
    float*    ad1  = w + o; o += (size_t)N * 4;
    unsigned* mx1  = (unsigned*)(w + o); o += (size_t)N * 4;
    float*    dn1  = w + o; o += (size_t)N * 4;
    float*    h2   = w + o; o += (size_t)N * 32;
    float*    as2  = w + o; o += (size_t)N;
    float*    ad2  = w + o; o += (size_t)N;
    unsigned* mx2  = (unsigned*)(w + o); o += (size_t)N;
    float*    dn2  = w + o; o += (size_t)N;

    // zero the accumulators (ws/d_out are poisoned before every launch)
    hipMemsetAsync(acc1, 0, (size_t)N * 128 * 4, stream);
    hipMemsetAsync(mx1, 0, (size_t)N * 8 * 4, stream);   // mx1 + dn1 (adjacent)
    hipMemsetAsync(mx2, 0, (size_t)N * 2 * 4, stream);   // mx2 + dn2 (adjacent)
    hipMemsetAsync(out, 0, (size_t)N * 32 * 4, stream);

    const int nb = (N + 63) / 64;

    // ---- layer 1 (H=4, C=32)
    gemm1_att<<<nb, 256, 0, stream>>>(x, W1, as1v, ad1v, h1, as1, ad1, N);
    {
        long long tot = (long long)(E + N) * 4;
        edge_max_k<4><<<(unsigned)((tot + 255) / 256), 256, 0, stream>>>(ei, E, N, as1, ad1, mx1);
    }
    {
        long long tot = (long long)(E + N) * 128;
        edge_acc_k<4, 32><<<(unsigned)((tot + 255) / 256), 256, 0, stream>>>(
            ei, E, N, as1, ad1, mx1, h1, dn1, acc1);
    }
    norm_relu_k<<<(N * 128 + 255) / 256, 256, 0, stream>>>(acc1, dn1, b1, h1, N);
    // h1 now holds relu(out1 + b1)

    // ---- layer 2 (H=1, C=32)
    gemm2_att<<<nb, 256, 0, stream>>>(h1, W2, as2v, ad2v, h2, as2, ad2, N);
    {
        long long tot = (long long)(E + N);
        edge_max_k<1><<<(unsigned)((tot + 255) / 256), 256, 0, stream>>>(ei, E, N, as2, ad2, mx2);
    }
    {
        long long tot = (long long)(E + N) * 32;
        edge_acc_k<1, 32><<<(unsigned)((tot + 255) / 256), 256, 0, stream>>>(
            ei, E, N, as2, ad2, mx2, h2, dn2, out);
    }
    norm_out_k<<<(N * 32 + 255) / 256, 256, 0, stream>>>(dn2, b2, out, N);
}

// Round 2
// 826.055 us; speedup vs baseline: 1.9226x; 1.9226x over previous
//
#include <hip/hip_runtime.h>
#include <hip/hip_bf16.h>

// GAT 2-layer, fp32. N=100000, IN=128, L1: H=4,C=32 (HC=128), L2: H=1,C=32.
//
// R1: replaced float-atomic scatter (956 MB of device-scope RMW -> memory,
// 922 us) with device-built CSR (group edges by dst) + per-dst gather reduce
// in registers. CSR built once, shared by both layers. Softmax max/sum/norm
// all fused into the gather kernel (two passes over each dst segment).
// Self-loops are implicit: edge ids >= E map to (n,n).

__device__ __forceinline__ float lrelu(float v) { return v >= 0.f ? v : 0.2f * v; }

// ---------------- GEMM1: x[N,128] @ W[128,128] -> h[N,128]; fused a_src/a_dst (H=4,C=32)
__global__ __launch_bounds__(256) void gemm1_att(
    const float* __restrict__ x, const float* __restrict__ W,
    const float* __restrict__ atts, const float* __restrict__ attd,
    float* __restrict__ h, float* __restrict__ as_, float* __restrict__ ad_, int N) {
    __shared__ float xs[64][33];
    __shared__ float ws[32][132];
    const int t = threadIdx.x;
    const int n0 = blockIdx.x * 64;
    const int tcol = t & 31;        // 32 col-groups of 4 cols
    const int trow = t >> 5;        // 8 row-groups of 8 rows
    float acc[8][4];
#pragma unroll
    for (int i = 0; i < 8; i++) { acc[i][0]=0.f; acc[i][1]=0.f; acc[i][2]=0.f; acc[i][3]=0.f; }

    for (int k0 = 0; k0 < 128; k0 += 32) {
        {   // stage x tile 64x32
            int k = t & 31, r0 = t >> 5;
#pragma unroll
            for (int i = 0; i < 8; i++) {
                int r = r0 + i * 8;
                int n = n0 + r;
                xs[r][k] = (n < N) ? x[(size_t)n * 128 + k0 + k] : 0.f;
            }
        }
        {   // stage W tile 32x128
            int c = t & 127, kk = t >> 7;
#pragma unroll
            for (int i = 0; i < 16; i++) {
                int k = kk + i * 2;
                ws[k][c] = W[(k0 + k) * 128 + c];
            }
        }
        __syncthreads();
#pragma unroll
        for (int k = 0; k < 32; k++) {
            float4 wv = *(const float4*)&ws[k][tcol * 4];
#pragma unroll
            for (int i = 0; i < 8; i++) {
                float xv = xs[trow * 8 + i][k];
                acc[i][0] += xv * wv.x; acc[i][1] += xv * wv.y;
                acc[i][2] += xv * wv.z; acc[i][3] += xv * wv.w;
            }
        }
        __syncthreads();
    }

    const int head = tcol >> 3;           // 8 threads per head
    const int cbase = tcol * 4;           // output col base
    const int csub = cbase - head * 32;   // col within head
    float s0 = atts[head * 32 + csub + 0], s1 = atts[head * 32 + csub + 1],
          s2 = atts[head * 32 + csub + 2], s3 = atts[head * 32 + csub + 3];
    float d0 = attd[head * 32 + csub + 0], d1 = attd[head * 32 + csub + 1],
          d2 = attd[head * 32 + csub + 2], d3 = attd[head * 32 + csub + 3];
#pragma unroll
    for (int i = 0; i < 8; i++) {
        int n = n0 + trow * 8 + i;
        if (n < N) {
            float4 hv = make_float4(acc[i][0], acc[i][1], acc[i][2], acc[i][3]);
            *(float4*)&h[(size_t)n * 128 + cbase] = hv;
            float ps = acc[i][0]*s0 + acc[i][1]*s1 + acc[i][2]*s2 + acc[i][3]*s3;
            float pd = acc[i][0]*d0 + acc[i][1]*d1 + acc[i][2]*d2 + acc[i][3]*d3;
            ps += __shfl_xor(ps, 1); pd += __shfl_xor(pd, 1);
            ps += __shfl_xor(ps, 2); pd += __shfl_xor(pd, 2);
            ps += __shfl_xor(ps, 4); pd += __shfl_xor(pd, 4);
            if ((tcol & 7) == 0) { as_[n * 4 + head] = ps; ad_[n * 4 + head] = pd; }
        }
    }
}

// ---------------- GEMM2: h1[N,128] @ W2[128,32] -> h2[N,32]; fused a_src/a_dst (H=1,C=32)
__global__ __launch_bounds__(256) void gemm2_att(
    const float* __restrict__ x, const float* __restrict__ W,
    const float* __restrict__ atts, const float* __restrict__ attd,
    float* __restrict__ h, float* __restrict__ as_, float* __restrict__ ad_, int N) {
    __shared__ float xs[64][33];
    __shared__ float ws[32][33];
    const int t = threadIdx.x;
    const int n0 = blockIdx.x * 64;
    const int tcol = t & 31;   // one col each
    const int trow = t >> 5;   // 8 rows each
    float acc[8];
#pragma unroll
    for (int i = 0; i < 8; i++) acc[i] = 0.f;

    for (int k0 = 0; k0 < 128; k0 += 32) {
        {
            int k = t & 31, r0 = t >> 5;
#pragma unroll
            for (int i = 0; i < 8; i++) {
                int r = r0 + i * 8;
                int n = n0 + r;
                xs[r][k] = (n < N) ? x[(size_t)n * 128 + k0 + k] : 0.f;
            }
        }
        {
            int c = t & 31, kk = t >> 5;
#pragma unroll
            for (int i = 0; i < 4; i++) {
                int k = kk + i * 8;
                ws[k][c] = W[(k0 + k) * 32 + c];
            }
        }
        __syncthreads();
#pragma unroll
        for (int k = 0; k < 32; k++) {
            float wv = ws[k][tcol];
#pragma unroll
            for (int i = 0; i < 8; i++) acc[i] += xs[trow * 8 + i][k] * wv;
        }
        __syncthreads();
    }

    float sa = atts[tcol], da = attd[tcol];
#pragma unroll
    for (int i = 0; i < 8; i++) {
        int n = n0 + trow * 8 + i;
        if (n < N) {
            h[(size_t)n * 32 + tcol] = acc[i];
            float ps = acc[i] * sa;
            float pd = acc[i] * da;
#pragma unroll
            for (int m = 1; m < 32; m <<= 1) { ps += __shfl_xor(ps, m); pd += __shfl_xor(pd, m); }
            if (tcol == 0) { as_[n] = ps; ad_[n] = pd; }
        }
    }
}

// ---------------- CSR build: histogram -> scan -> scatter -------------------
__global__ __launch_bounds__(256) void hist_k(const int* __restrict__ ei, int E, int N,
                                              int* __restrict__ deg) {
    int e = blockIdx.x * 256 + threadIdx.x;
    if (e >= E + N) return;
    int d = (e < E) ? ei[E + e] : e - E;
    atomicAdd(&deg[d], 1);
}

__global__ __launch_bounds__(256) void scan1_k(const int* __restrict__ deg,
                                               int* __restrict__ tmp, int* __restrict__ partial, int N) {
    __shared__ int sh[256];
    int i = blockIdx.x * 256 + threadIdx.x;
    int v = (i < N) ? deg[i] : 0;
    sh[threadIdx.x] = v;
    __syncthreads();
#pragma unroll
    for (int off = 1; off < 256; off <<= 1) {
        int t = (threadIdx.x >= off) ? sh[threadIdx.x - off] : 0;
        __syncthreads();
        sh[threadIdx.x] += t;
        __syncthreads();
    }
    if (i < N) tmp[i] = sh[threadIdx.x];
    if (threadIdx.x == 255) partial[blockIdx.x] = sh[255];
}

// single block, exclusive scan of partial[B] (B <= 1024)
__global__ __launch_bounds__(1024) void scan2_k(int* __restrict__ partial, int B) {
    __shared__ int sh[1024];
    int i = threadIdx.x;
    int v = (i < B) ? partial[i] : 0;
    sh[i] = v;
    __syncthreads();
#pragma unroll
    for (int off = 1; off < 1024; off <<= 1) {
        int t = (i >= off) ? sh[i - off] : 0;
        __syncthreads();
        sh[i] += t;
        __syncthreads();
    }
    if (i < B) partial[i] = sh[i] - v;   // exclusive
}

__global__ __launch_bounds__(256) void scan3_k(const int* __restrict__ tmp, const int* __restrict__ partial,
                                               const int* __restrict__ deg,
                                               int* __restrict__ rs, int* __restrict__ cursor, int N) {
    int i = blockIdx.x * 256 + threadIdx.x;
    if (i < N) {
        int incl = tmp[i] + partial[blockIdx.x];
        rs[i + 1] = incl;
        cursor[i] = incl - deg[i];
    }
    if (i == 0) rs[0] = 0;
}

__global__ __launch_bounds__(256) void scatter_k(const int* __restrict__ ei, int E, int N,
                                                 int* __restrict__ cursor, int* __restrict__ csr) {
    int e = blockIdx.x * 256 + threadIdx.x;
    if (e >= E + N) return;
    int s, d;
    if (e < E) { s = ei[e]; d = ei[E + e]; } else { s = e - E; d = s; }
    int pos = atomicAdd(&cursor[d], 1);
    csr[pos] = s;
}

// ---------------- layer-1 gather: one block(128) per dst, fused softmax+norm+bias+relu
__global__ __launch_bounds__(128) void gather1_k(
    const int* __restrict__ rs, const int* __restrict__ csr,
    const float* __restrict__ as_, const float* __restrict__ ad_,
    const float* __restrict__ h, const float* __restrict__ b,
    float* __restrict__ o, int N) {
    const int d = blockIdx.x;
    const int ch = threadIdx.x;          // 0..127
    const int hh = ch >> 5;              // head
    const int beg = rs[d], end = rs[d + 1];
    const float adv = ad_[d * 4 + hh];
    const float bv = b[ch];

    float m = -1e30f;
    for (int j = beg; j < end; j++) {
        int s = csr[j];
        m = fmaxf(m, lrelu(as_[s * 4 + hh] + adv));
    }
    float acc = 0.f, den = 0.f;
    int s_next = csr[beg];
    for (int j = beg; j < end; j++) {
        int s = s_next;
        if (j + 1 < end) s_next = csr[j + 1];
        float e = lrelu(as_[s * 4 + hh] + adv);
        float ex = __expf(e - m);
        den += ex;
        acc += ex * h[(size_t)s * 128 + ch];
    }
    float v = acc / (den + 1e-16f) + bv;
    o[(size_t)d * 128 + ch] = v > 0.f ? v : 0.f;
}

// ---------------- layer-2 gather: 8 dsts per block(256), 32 lanes each; fused bias
__global__ __launch_bounds__(256) void gather2_k(
    const int* __restrict__ rs, const int* __restrict__ csr,
    const float* __restrict__ as_, const float* __restrict__ ad_,
    const float* __restrict__ h, const float* __restrict__ b,
    float* __restrict__ o, int N) {
    const int d = blockIdx.x * 8 + (threadIdx.x >> 5);
    const int ch = threadIdx.x & 31;
    if (d >= N) return;
    const int beg = rs[d], end = rs[d + 1];
    const float adv = ad_[d];
    const float bv = b[ch];

    float m = -1e30f;
    for (int j = beg; j < end; j++) {
        int s = csr[j];
        m = fmaxf(m, lrelu(as_[s] + adv));
    }
    float acc = 0.f, den = 0.f;
    int s_next = csr[beg];
    for (int j = beg; j < end; j++) {
        int s = s_next;
        if (j + 1 < end) s_next = csr[j + 1];
        float e = lrelu(as_[s] + adv);
        float ex = __expf(e - m);
        den += ex;
        acc += ex * h[(size_t)s * 32 + ch];
    }
    o[(size_t)d * 32 + ch] = acc / (den + 1e-16f) + bv;
}

extern "C" void kernel_launch(void* const* d_in, const int* in_sizes, int n_in,
                              void* d_out, int out_size, void* d_ws, size_t ws_size,
                              hipStream_t stream) {
    const float* x    = (const float*)d_in[0];
    const int*   ei   = (const int*)d_in[1];
    const float* W1   = (const float*)d_in[2];
    const float* as1v = (const float*)d_in[3];
    const float* ad1v = (const float*)d_in[4];
    const float* b1   = (const float*)d_in[5];
    const float* W2   = (const float*)d_in[6];
    const float* as2v = (const float*)d_in[7];
    const float* ad2v = (const float*)d_in[8];
    const float* b2   = (const float*)d_in[9];
    float* out = (float*)d_out;

    const int N = in_sizes[0] / 128;
    const int E = in_sizes[1] / 2;
    const int EN = E + N;
    const int B = (N + 255) / 256;   // scan chunks (must be <= 1024)

    // workspace layout
    char* base = (char*)d_ws;
    size_t o = 0;
    auto alloc = [&](size_t bytes) { void* p = base + o; o += (bytes + 255) & ~(size_t)255; return p; };
    float* h1   = (float*)alloc((size_t)N * 128 * 4);
    float* h2   = (float*)alloc((size_t)N * 32 * 4);
    float* as1  = (float*)alloc((size_t)N * 4 * 4);
    float* ad1  = (float*)alloc((size_t)N * 4 * 4);
    float* as2  = (float*)alloc((size_t)N * 4);
    float* ad2  = (float*)alloc((size_t)N * 4);
    int*   deg  = (int*)alloc((size_t)N * 4);
    int*   tmp  = (int*)alloc((size_t)N * 4);
    int*   part = (int*)alloc((size_t)1024 * 4);
    int*   rs   = (int*)alloc((size_t)(N + 1) * 4);
    int*   cur  = (int*)alloc((size_t)N * 4);
    int*   csr  = (int*)alloc((size_t)EN * 4);

    hipMemsetAsync(deg, 0, (size_t)N * 4, stream);

    const int nbE = (EN + 255) / 256;
    const int nbN = (N + 255) / 256;
    const int nbG = (N + 63) / 64;

    // ---- CSR build (shared by both layers) + layer-1 GEMM
    gemm1_att<<<nbG, 256, 0, stream>>>(x, W1, as1v, ad1v, h1, as1, ad1, N);
    hist_k<<<nbE, 256, 0, stream>>>(ei, E, N, deg);
    scan1_k<<<nbN, 256, 0, stream>>>(deg, tmp, part, N);
    scan2_k<<<1, 1024, 0, stream>>>(part, B);
    scan3_k<<<nbN, 256, 0, stream>>>(tmp, part, deg, rs, cur, N);
    scatter_k<<<nbE, 256, 0, stream>>>(ei, E, N, cur, csr);

    // ---- layer 1 edge softmax + aggregate + bias + relu -> h1 (in place ok: reads h1, writes h1? NO)
    // gather1 reads h1 rows of OTHER nodes while writing own row -> need separate out buf.
    // reuse: write into a fresh buffer (alias h2 region is too small) -> allocate o1.
    {
        static_assert(sizeof(float) == 4, "");
    }
    float* o1 = (float*)alloc((size_t)N * 128 * 4);
    gather1_k<<<N, 128, 0, stream>>>(rs, csr, as1, ad1, h1, b1, o1, N);

    // ---- layer 2
    gemm2_att<<<nbG, 256, 0, stream>>>(o1, W2, as2v, ad2v, h2, as2, ad2, N);
    gather2_k<<<(N + 7) / 8, 256, 0, stream>>>(rs, csr, as2, ad2, h2, b2, out, N);
}

// Round 3
// 734.285 us; speedup vs baseline: 2.1629x; 1.1250x over previous
//
#include <hip/hip_runtime.h>
#include <hip/hip_bf16.h>

// GAT 2-layer, fp32. N=100000, IN=128, L1: H=4,C=32 (HC=128), L2: H=1,C=32.
//
// R1: CSR gather instead of float-atomic scatter (1588 -> 826 us).
// R2: gathers were VALU-bound (57% busy) on 32x-redundant per-(edge,head)
// softmax math (218M expf). Now: per-head 32-lane cooperative softmax
// (shfl-reduce max/denom), alpha computed once per edge and broadcast via
// __shfl in 32-edge chunks. No LDS, no __syncthreads in the gathers.
// Self-loops are implicit: edge ids >= E map to (n,n).

__device__ __forceinline__ float lrelu(float v) { return v >= 0.f ? v : 0.2f * v; }

// ---------------- GEMM1: x[N,128] @ W[128,128] -> h[N,128]; fused a_src/a_dst (H=4,C=32)
__global__ __launch_bounds__(256) void gemm1_att(
    const float* __restrict__ x, const float* __restrict__ W,
    const float* __restrict__ atts, const float* __restrict__ attd,
    float* __restrict__ h, float* __restrict__ as_, float* __restrict__ ad_, int N) {
    __shared__ float xs[64][33];
    __shared__ float ws[32][132];
    const int t = threadIdx.x;
    const int n0 = blockIdx.x * 64;
    const int tcol = t & 31;        // 32 col-groups of 4 cols
    const int trow = t >> 5;        // 8 row-groups of 8 rows
    float acc[8][4];
#pragma unroll
    for (int i = 0; i < 8; i++) { acc[i][0]=0.f; acc[i][1]=0.f; acc[i][2]=0.f; acc[i][3]=0.f; }

    for (int k0 = 0; k0 < 128; k0 += 32) {
        {   // stage x tile 64x32
            int k = t & 31, r0 = t >> 5;
#pragma unroll
            for (int i = 0; i < 8; i++) {
                int r = r0 + i * 8;
                int n = n0 + r;
                xs[r][k] = (n < N) ? x[(size_t)n * 128 + k0 + k] : 0.f;
            }
        }
        {   // stage W tile 32x128
            int c = t & 127, kk = t >> 7;
#pragma unroll
            for (int i = 0; i < 16; i++) {
                int k = kk + i * 2;
                ws[k][c] = W[(k0 + k) * 128 + c];
            }
        }
        __syncthreads();
#pragma unroll
        for (int k = 0; k < 32; k++) {
            float4 wv = *(const float4*)&ws[k][tcol * 4];
#pragma unroll
            for (int i = 0; i < 8; i++) {
                float xv = xs[trow * 8 + i][k];
                acc[i][0] += xv * wv.x; acc[i][1] += xv * wv.y;
                acc[i][2] += xv * wv.z; acc[i][3] += xv * wv.w;
            }
        }
        __syncthreads();
    }

    const int head = tcol >> 3;           // 8 threads per head
    const int cbase = tcol * 4;           // output col base
    const int csub = cbase - head * 32;   // col within head
    float s0 = atts[head * 32 + csub + 0], s1 = atts[head * 32 + csub + 1],
          s2 = atts[head * 32 + csub + 2], s3 = atts[head * 32 + csub + 3];
    float d0 = attd[head * 32 + csub + 0], d1 = attd[head * 32 + csub + 1],
          d2 = attd[head * 32 + csub + 2], d3 = attd[head * 32 + csub + 3];
#pragma unroll
    for (int i = 0; i < 8; i++) {
        int n = n0 + trow * 8 + i;
        if (n < N) {
            float4 hv = make_float4(acc[i][0], acc[i][1], acc[i][2], acc[i][3]);
            *(float4*)&h[(size_t)n * 128 + cbase] = hv;
            float ps = acc[i][0]*s0 + acc[i][1]*s1 + acc[i][2]*s2 + acc[i][3]*s3;
            float pd = acc[i][0]*d0 + acc[i][1]*d1 + acc[i][2]*d2 + acc[i][3]*d3;
            ps += __shfl_xor(ps, 1); pd += __shfl_xor(pd, 1);
            ps += __shfl_xor(ps, 2); pd += __shfl_xor(pd, 2);
            ps += __shfl_xor(ps, 4); pd += __shfl_xor(pd, 4);
            if ((tcol & 7) == 0) { as_[n * 4 + head] = ps; ad_[n * 4 + head] = pd; }
        }
    }
}

// ---------------- GEMM2: h1[N,128] @ W2[128,32] -> h2[N,32]; fused a_src/a_dst (H=1,C=32)
__global__ __launch_bounds__(256) void gemm2_att(
    const float* __restrict__ x, const float* __restrict__ W,
    const float* __restrict__ atts, const float* __restrict__ attd,
    float* __restrict__ h, float* __restrict__ as_, float* __restrict__ ad_, int N) {
    __shared__ float xs[64][33];
    __shared__ float ws[32][33];
    const int t = threadIdx.x;
    const int n0 = blockIdx.x * 64;
    const int tcol = t & 31;   // one col each
    const int trow = t >> 5;   // 8 rows each
    float acc[8];
#pragma unroll
    for (int i = 0; i < 8; i++) acc[i] = 0.f;

    for (int k0 = 0; k0 < 128; k0 += 32) {
        {
            int k = t & 31, r0 = t >> 5;
#pragma unroll
            for (int i = 0; i < 8; i++) {
                int r = r0 + i * 8;
                int n = n0 + r;
                xs[r][k] = (n < N) ? x[(size_t)n * 128 + k0 + k] : 0.f;
            }
        }
        {
            int c = t & 31, kk = t >> 5;
#pragma unroll
            for (int i = 0; i < 4; i++) {
                int k = kk + i * 8;
                ws[k][c] = W[(k0 + k) * 32 + c];
            }
        }
        __syncthreads();
#pragma unroll
        for (int k = 0; k < 32; k++) {
            float wv = ws[k][tcol];
#pragma unroll
            for (int i = 0; i < 8; i++) acc[i] += xs[trow * 8 + i][k] * wv;
        }
        __syncthreads();
    }

    float sa = atts[tcol], da = attd[tcol];
#pragma unroll
    for (int i = 0; i < 8; i++) {
        int n = n0 + trow * 8 + i;
        if (n < N) {
            h[(size_t)n * 32 + tcol] = acc[i];
            float ps = acc[i] * sa;
            float pd = acc[i] * da;
#pragma unroll
            for (int m = 1; m < 32; m <<= 1) { ps += __shfl_xor(ps, m); pd += __shfl_xor(pd, m); }
            if (tcol == 0) { as_[n] = ps; ad_[n] = pd; }
        }
    }
}

// ---------------- CSR build: histogram -> scan -> scatter -------------------
__global__ __launch_bounds__(256) void hist_k(const int* __restrict__ ei, int E, int N,
                                              int* __restrict__ deg) {
    int e = blockIdx.x * 256 + threadIdx.x;
    if (e >= E + N) return;
    int d = (e < E) ? ei[E + e] : e - E;
    atomicAdd(&deg[d], 1);
}

__global__ __launch_bounds__(256) void scan1_k(const int* __restrict__ deg,
                                               int* __restrict__ tmp, int* __restrict__ partial, int N) {
    __shared__ int sh[256];
    int i = blockIdx.x * 256 + threadIdx.x;
    int v = (i < N) ? deg[i] : 0;
    sh[threadIdx.x] = v;
    __syncthreads();
#pragma unroll
    for (int off = 1; off < 256; off <<= 1) {
        int t = (threadIdx.x >= off) ? sh[threadIdx.x - off] : 0;
        __syncthreads();
        sh[threadIdx.x] += t;
        __syncthreads();
    }
    if (i < N) tmp[i] = sh[threadIdx.x];
    if (threadIdx.x == 255) partial[blockIdx.x] = sh[255];
}

// single block, exclusive scan of partial[B] (B <= 1024)
__global__ __launch_bounds__(1024) void scan2_k(int* __restrict__ partial, int B) {
    __shared__ int sh[1024];
    int i = threadIdx.x;
    int v = (i < B) ? partial[i] : 0;
    sh[i] = v;
    __syncthreads();
#pragma unroll
    for (int off = 1; off < 1024; off <<= 1) {
        int t = (i >= off) ? sh[i - off] : 0;
        __syncthreads();
        sh[i] += t;
        __syncthreads();
    }
    if (i < B) partial[i] = sh[i] - v;   // exclusive
}

__global__ __launch_bounds__(256) void scan3_k(const int* __restrict__ tmp, const int* __restrict__ partial,
                                               const int* __restrict__ deg,
                                               int* __restrict__ rs, int* __restrict__ cursor, int N) {
    int i = blockIdx.x * 256 + threadIdx.x;
    if (i < N) {
        int incl = tmp[i] + partial[blockIdx.x];
        rs[i + 1] = incl;
        cursor[i] = incl - deg[i];
    }
    if (i == 0) rs[0] = 0;
}

__global__ __launch_bounds__(256) void scatter_k(const int* __restrict__ ei, int E, int N,
                                                 int* __restrict__ cursor, int* __restrict__ csr) {
    int e = blockIdx.x * 256 + threadIdx.x;
    if (e >= E + N) return;
    int s, d;
    if (e < E) { s = ei[e]; d = ei[E + e]; } else { s = e - E; d = s; }
    int pos = atomicAdd(&cursor[d], 1);
    csr[pos] = s;
}

// ---------------- layer-1 gather: one block(128) per dst.
// Lane role: hh = t>>5 (head), jj = t&31 (edge slot). Softmax stats via
// 32-lane shfl reduce; alpha computed once per (edge,head) and shfl-broadcast.
__global__ __launch_bounds__(128) void gather1_k(
    const int* __restrict__ rs, const int* __restrict__ csr,
    const float* __restrict__ as_, const float* __restrict__ ad_,
    const float* __restrict__ h, const float* __restrict__ b,
    float* __restrict__ o, int N) {
    const int d = blockIdx.x;
    const int t = threadIdx.x;          // 0..127 (= output channel)
    const int hh = t >> 5;              // head
    const int jj = t & 31;              // edge slot within chunk
    const int beg = rs[d], end = rs[d + 1];
    const float adv = ad_[d * 4 + hh];

    // phase A: per-head max, then denom (strided over segment, shfl-reduced)
    float m = -1e30f;
    for (int j = beg + jj; j < end; j += 32) {
        int s = csr[j];
        m = fmaxf(m, lrelu(as_[s * 4 + hh] + adv));
    }
#pragma unroll
    for (int k = 1; k < 32; k <<= 1) m = fmaxf(m, __shfl_xor(m, k, 32));

    float den = 0.f;
    for (int j = beg + jj; j < end; j += 32) {
        int s = csr[j];
        den += __expf(lrelu(as_[s * 4 + hh] + adv) - m);
    }
#pragma unroll
    for (int k = 1; k < 32; k <<= 1) den += __shfl_xor(den, k, 32);
    const float rcp = 1.f / (den + 1e-16f);

    // phase B: 32-edge chunks; lane jj owns alpha/src for edge j0+jj,
    // broadcast via shfl, every lane fmas its own channel.
    float acc = 0.f;
    for (int j0 = beg; j0 < end; j0 += 32) {
        int j = j0 + jj;
        float alpha = 0.f;
        int sreg = 0;
        if (j < end) {
            sreg = csr[j];
            alpha = __expf(lrelu(as_[sreg * 4 + hh] + adv) - m) * rcp;
        }
        int lim = min(32, end - j0);
        for (int q = 0; q < lim; q++) {
            float a = __shfl(alpha, q, 32);
            int s = __shfl(sreg, q, 32);
            acc += a * h[(size_t)s * 128 + t];
        }
    }
    float v = acc + b[t];
    o[(size_t)d * 128 + t] = v > 0.f ? v : 0.f;
}

// ---------------- layer-2 gather: 8 dsts per block(256), 32 lanes per dst.
__global__ __launch_bounds__(256) void gather2_k(
    const int* __restrict__ rs, const int* __restrict__ csr,
    const float* __restrict__ as_, const float* __restrict__ ad_,
    const float* __restrict__ h, const float* __restrict__ b,
    float* __restrict__ o, int N) {
    const int d = blockIdx.x * 8 + (threadIdx.x >> 5);
    const int ch = threadIdx.x & 31;    // channel AND edge slot
    if (d >= N) return;
    const int beg = rs[d], end = rs[d + 1];
    const float adv = ad_[d];

    float m = -1e30f;
    for (int j = beg + ch; j < end; j += 32) {
        m = fmaxf(m, lrelu(as_[csr[j]] + adv));
    }
#pragma unroll
    for (int k = 1; k < 32; k <<= 1) m = fmaxf(m, __shfl_xor(m, k, 32));

    float den = 0.f;
    for (int j = beg + ch; j < end; j += 32) {
        den += __expf(lrelu(as_[csr[j]] + adv) - m);
    }
#pragma unroll
    for (int k = 1; k < 32; k <<= 1) den += __shfl_xor(den, k, 32);
    const float rcp = 1.f / (den + 1e-16f);

    float acc = 0.f;
    for (int j0 = beg; j0 < end; j0 += 32) {
        int j = j0 + ch;
        float alpha = 0.f;
        int sreg = 0;
        if (j < end) {
            sreg = csr[j];
            alpha = __expf(lrelu(as_[sreg] + adv) - m) * rcp;
        }
        int lim = min(32, end - j0);
        for (int q = 0; q < lim; q++) {
            float a = __shfl(alpha, q, 32);
            int s = __shfl(sreg, q, 32);
            acc += a * h[(size_t)s * 32 + ch];
        }
    }
    o[(size_t)d * 32 + ch] = acc + b[ch];
}

extern "C" void kernel_launch(void* const* d_in, const int* in_sizes, int n_in,
                              void* d_out, int out_size, void* d_ws, size_t ws_size,
                              hipStream_t stream) {
    const float* x    = (const float*)d_in[0];
    const int*   ei   = (const int*)d_in[1];
    const float* W1   = (const float*)d_in[2];
    const float* as1v = (const float*)d_in[3];
    const float* ad1v = (const float*)d_in[4];
    const float* b1   = (const float*)d_in[5];
    const float* W2   = (const float*)d_in[6];
    const float* as2v = (const float*)d_in[7];
    const float* ad2v = (const float*)d_in[8];
    const float* b2   = (const float*)d_in[9];
    float* out = (float*)d_out;

    const int N = in_sizes[0] / 128;
    const int E = in_sizes[1] / 2;
    const int EN = E + N;
    const int B = (N + 255) / 256;   // scan chunks (must be <= 1024)

    // workspace layout
    char* base = (char*)d_ws;
    size_t o = 0;
    auto alloc = [&](size_t bytes) { void* p = base + o; o += (bytes + 255) & ~(size_t)255; return p; };
    float* h1   = (float*)alloc((size_t)N * 128 * 4);
    float* h2   = (float*)alloc((size_t)N * 32 * 4);
    float* as1  = (float*)alloc((size_t)N * 4 * 4);
    float* ad1  = (float*)alloc((size_t)N * 4 * 4);
    float* as2  = (float*)alloc((size_t)N * 4);
    float* ad2  = (float*)alloc((size_t)N * 4);
    int*   deg  = (int*)alloc((size_t)N * 4);
    int*   tmp  = (int*)alloc((size_t)N * 4);
    int*   part = (int*)alloc((size_t)1024 * 4);
    int*   rs   = (int*)alloc((size_t)(N + 1) * 4);
    int*   cur  = (int*)alloc((size_t)N * 4);
    int*   csr  = (int*)alloc((size_t)EN * 4);
    float* o1   = (float*)alloc((size_t)N * 128 * 4);

    hipMemsetAsync(deg, 0, (size_t)N * 4, stream);

    const int nbE = (EN + 255) / 256;
    const int nbN = (N + 255) / 256;
    const int nbG = (N + 63) / 64;

    // ---- layer-1 GEMM + CSR build (shared by both layers)
    gemm1_att<<<nbG, 256, 0, stream>>>(x, W1, as1v, ad1v, h1, as1, ad1, N);
    hist_k<<<nbE, 256, 0, stream>>>(ei, E, N, deg);
    scan1_k<<<nbN, 256, 0, stream>>>(deg, tmp, part, N);
    scan2_k<<<1, 1024, 0, stream>>>(part, B);
    scan3_k<<<nbN, 256, 0, stream>>>(tmp, part, deg, rs, cur, N);
    scatter_k<<<nbE, 256, 0, stream>>>(ei, E, N, cur, csr);

    // ---- layer 1 edge softmax + aggregate + bias + relu -> o1
    gather1_k<<<N, 128, 0, stream>>>(rs, csr, as1, ad1, h1, b1, o1, N);

    // ---- layer 2
    gemm2_att<<<nbG, 256, 0, stream>>>(o1, W2, as2v, ad2v, h2, as2, ad2, N);
    gather2_k<<<(N + 7) / 8, 256, 0, stream>>>(rs, csr, as2, ad2, h2, b2, out, N);
}

// Round 4
// 595.368 us; speedup vs baseline: 2.6676x; 1.2333x over previous
//
#include <hip/hip_runtime.h>
#include <hip/hip_bf16.h>

// GAT 2-layer, fp32. N=100000, IN=128, L1: H=4,C=32 (HC=128), L2: H=1,C=32.
//
// R1: CSR gather instead of float-atomic scatter (1588 -> 826 us).
// R2: cooperative softmax, alpha shfl-broadcast (826 -> 734; gather1 240us,
//     latency-bound: rolled inner loop = 1 outstanding 4B load).
// R3: single-pass unnormalized softmax (normalize in epilogue; exp clamped
//     at 80 so no overflow), float4 h loads (16B/lane), 8-edge chunks fully
//     unrolled -> 8 loads in flight. One dst per 32-lane group (gather1),
//     4 dsts per group (gather2). All shfls within 8-lane subgroups.
// Self-loops are implicit: edge ids >= E map to (n,n).

__device__ __forceinline__ float lrelu(float v) { return v >= 0.f ? v : 0.2f * v; }

// ---------------- GEMM1: x[N,128] @ W[128,128] -> h[N,128]; fused a_src/a_dst (H=4,C=32)
__global__ __launch_bounds__(256) void gemm1_att(
    const float* __restrict__ x, const float* __restrict__ W,
    const float* __restrict__ atts, const float* __restrict__ attd,
    float* __restrict__ h, float* __restrict__ as_, float* __restrict__ ad_, int N) {
    __shared__ float xs[64][33];
    __shared__ float ws[32][132];
    const int t = threadIdx.x;
    const int n0 = blockIdx.x * 64;
    const int tcol = t & 31;        // 32 col-groups of 4 cols
    const int trow = t >> 5;        // 8 row-groups of 8 rows
    float acc[8][4];
#pragma unroll
    for (int i = 0; i < 8; i++) { acc[i][0]=0.f; acc[i][1]=0.f; acc[i][2]=0.f; acc[i][3]=0.f; }

    for (int k0 = 0; k0 < 128; k0 += 32) {
        {   // stage x tile 64x32
            int k = t & 31, r0 = t >> 5;
#pragma unroll
            for (int i = 0; i < 8; i++) {
                int r = r0 + i * 8;
                int n = n0 + r;
                xs[r][k] = (n < N) ? x[(size_t)n * 128 + k0 + k] : 0.f;
            }
        }
        {   // stage W tile 32x128
            int c = t & 127, kk = t >> 7;
#pragma unroll
            for (int i = 0; i < 16; i++) {
                int k = kk + i * 2;
                ws[k][c] = W[(k0 + k) * 128 + c];
            }
        }
        __syncthreads();
#pragma unroll
        for (int k = 0; k < 32; k++) {
            float4 wv = *(const float4*)&ws[k][tcol * 4];
#pragma unroll
            for (int i = 0; i < 8; i++) {
                float xv = xs[trow * 8 + i][k];
                acc[i][0] += xv * wv.x; acc[i][1] += xv * wv.y;
                acc[i][2] += xv * wv.z; acc[i][3] += xv * wv.w;
            }
        }
        __syncthreads();
    }

    const int head = tcol >> 3;           // 8 threads per head
    const int cbase = tcol * 4;           // output col base
    const int csub = cbase - head * 32;   // col within head
    float s0 = atts[head * 32 + csub + 0], s1 = atts[head * 32 + csub + 1],
          s2 = atts[head * 32 + csub + 2], s3 = atts[head * 32 + csub + 3];
    float d0 = attd[head * 32 + csub + 0], d1 = attd[head * 32 + csub + 1],
          d2 = attd[head * 32 + csub + 2], d3 = attd[head * 32 + csub + 3];
#pragma unroll
    for (int i = 0; i < 8; i++) {
        int n = n0 + trow * 8 + i;
        if (n < N) {
            float4 hv = make_float4(acc[i][0], acc[i][1], acc[i][2], acc[i][3]);
            *(float4*)&h[(size_t)n * 128 + cbase] = hv;
            float ps = acc[i][0]*s0 + acc[i][1]*s1 + acc[i][2]*s2 + acc[i][3]*s3;
            float pd = acc[i][0]*d0 + acc[i][1]*d1 + acc[i][2]*d2 + acc[i][3]*d3;
            ps += __shfl_xor(ps, 1); pd += __shfl_xor(pd, 1);
            ps += __shfl_xor(ps, 2); pd += __shfl_xor(pd, 2);
            ps += __shfl_xor(ps, 4); pd += __shfl_xor(pd, 4);
            if ((tcol & 7) == 0) { as_[n * 4 + head] = ps; ad_[n * 4 + head] = pd; }
        }
    }
}

// ---------------- GEMM2: h1[N,128] @ W2[128,32] -> h2[N,32]; fused a_src/a_dst (H=1,C=32)
__global__ __launch_bounds__(256) void gemm2_att(
    const float* __restrict__ x, const float* __restrict__ W,
    const float* __restrict__ atts, const float* __restrict__ attd,
    float* __restrict__ h, float* __restrict__ as_, float* __restrict__ ad_, int N) {
    __shared__ float xs[64][33];
    __shared__ float ws[32][33];
    const int t = threadIdx.x;
    const int n0 = blockIdx.x * 64;
    const int tcol = t & 31;   // one col each
    const int trow = t >> 5;   // 8 rows each
    float acc[8];
#pragma unroll
    for (int i = 0; i < 8; i++) acc[i] = 0.f;

    for (int k0 = 0; k0 < 128; k0 += 32) {
        {
            int k = t & 31, r0 = t >> 5;
#pragma unroll
            for (int i = 0; i < 8; i++) {
                int r = r0 + i * 8;
                int n = n0 + r;
                xs[r][k] = (n < N) ? x[(size_t)n * 128 + k0 + k] : 0.f;
            }
        }
        {
            int c = t & 31, kk = t >> 5;
#pragma unroll
            for (int i = 0; i < 4; i++) {
                int k = kk + i * 8;
                ws[k][c] = W[(k0 + k) * 32 + c];
            }
        }
        __syncthreads();
#pragma unroll
        for (int k = 0; k < 32; k++) {
            float wv = ws[k][tcol];
#pragma unroll
            for (int i = 0; i < 8; i++) acc[i] += xs[trow * 8 + i][k] * wv;
        }
        __syncthreads();
    }

    float sa = atts[tcol], da = attd[tcol];
#pragma unroll
    for (int i = 0; i < 8; i++) {
        int n = n0 + trow * 8 + i;
        if (n < N) {
            h[(size_t)n * 32 + tcol] = acc[i];
            float ps = acc[i] * sa;
            float pd = acc[i] * da;
#pragma unroll
            for (int m = 1; m < 32; m <<= 1) { ps += __shfl_xor(ps, m); pd += __shfl_xor(pd, m); }
            if (tcol == 0) { as_[n] = ps; ad_[n] = pd; }
        }
    }
}

// ---------------- CSR build: histogram -> scan -> scatter -------------------
__global__ __launch_bounds__(256) void hist_k(const int* __restrict__ ei, int E, int N,
                                              int* __restrict__ deg) {
    int e = blockIdx.x * 256 + threadIdx.x;
    if (e >= E + N) return;
    int d = (e < E) ? ei[E + e] : e - E;
    atomicAdd(&deg[d], 1);
}

__global__ __launch_bounds__(256) void scan1_k(const int* __restrict__ deg,
                                               int* __restrict__ tmp, int* __restrict__ partial, int N) {
    __shared__ int sh[256];
    int i = blockIdx.x * 256 + threadIdx.x;
    int v = (i < N) ? deg[i] : 0;
    sh[threadIdx.x] = v;
    __syncthreads();
#pragma unroll
    for (int off = 1; off < 256; off <<= 1) {
        int t = (threadIdx.x >= off) ? sh[threadIdx.x - off] : 0;
        __syncthreads();
        sh[threadIdx.x] += t;
        __syncthreads();
    }
    if (i < N) tmp[i] = sh[threadIdx.x];
    if (threadIdx.x == 255) partial[blockIdx.x] = sh[255];
}

// single block, exclusive scan of partial[B] (B <= 1024)
__global__ __launch_bounds__(1024) void scan2_k(int* __restrict__ partial, int B) {
    __shared__ int sh[1024];
    int i = threadIdx.x;
    int v = (i < B) ? partial[i] : 0;
    sh[i] = v;
    __syncthreads();
#pragma unroll
    for (int off = 1; off < 1024; off <<= 1) {
        int t = (i >= off) ? sh[i - off] : 0;
        __syncthreads();
        sh[i] += t;
        __syncthreads();
    }
    if (i < B) partial[i] = sh[i] - v;   // exclusive
}

__global__ __launch_bounds__(256) void scan3_k(const int* __restrict__ tmp, const int* __restrict__ partial,
                                               const int* __restrict__ deg,
                                               int* __restrict__ rs, int* __restrict__ cursor, int N) {
    int i = blockIdx.x * 256 + threadIdx.x;
    if (i < N) {
        int incl = tmp[i] + partial[blockIdx.x];
        rs[i + 1] = incl;
        cursor[i] = incl - deg[i];
    }
    if (i == 0) rs[0] = 0;
}

__global__ __launch_bounds__(256) void scatter_k(const int* __restrict__ ei, int E, int N,
                                                 int* __restrict__ cursor, int* __restrict__ csr) {
    int e = blockIdx.x * 256 + threadIdx.x;
    if (e >= E + N) return;
    int s, d;
    if (e < E) { s = ei[e]; d = ei[E + e]; } else { s = e - E; d = s; }
    int pos = atomicAdd(&cursor[d], 1);
    csr[pos] = s;
}

// ---------------- layer-1 gather: one dst per 32-lane group, 8 dsts/block.
// Lane jj: channels 4jj..4jj+3 (head hh=jj>>3); also owns softmax term for
// (edge-slot es=jj&7, head hh). Single pass: unnormalized num+den, scale at end.
__global__ __launch_bounds__(256) void gather1_k(
    const int* __restrict__ rs, const int* __restrict__ csr,
    const float* __restrict__ as_, const float* __restrict__ ad_,
    const float* __restrict__ h, const float* __restrict__ b,
    float* __restrict__ o, int N) {
    const int d = blockIdx.x * 8 + (threadIdx.x >> 5);
    if (d >= N) return;
    const int jj = threadIdx.x & 31;
    const int hh = jj >> 3;
    const int es = jj & 7;
    const int sub = jj & 24;            // base lane of my 8-lane subgroup
    const int beg = rs[d], end = rs[d + 1];
    const float adv = ad_[d * 4 + hh];

    float4 acc = make_float4(0.f, 0.f, 0.f, 0.f);
    float den = 0.f;
    int j0 = beg;
    for (; j0 + 8 <= end; j0 += 8) {
        int s_own = csr[j0 + es];
        float e = lrelu(as_[s_own * 4 + hh] + adv);
        float ex = __expf(fminf(e, 80.f));
        den += ex;
#pragma unroll
        for (int q = 0; q < 8; q++) {
            float a = __shfl(ex, sub + q, 32);
            int s = __shfl(s_own, sub + q, 32);
            float4 hv = *(const float4*)&h[(size_t)s * 128 + jj * 4];
            acc.x += a * hv.x; acc.y += a * hv.y;
            acc.z += a * hv.z; acc.w += a * hv.w;
        }
    }
    int r = end - j0;
    if (r > 0) {
        int s_own = 0; float ex = 0.f;
        if (es < r) {
            s_own = csr[j0 + es];
            float e = lrelu(as_[s_own * 4 + hh] + adv);
            ex = __expf(fminf(e, 80.f));
        }
        den += ex;
        for (int q = 0; q < r; q++) {
            float a = __shfl(ex, sub + q, 32);
            int s = __shfl(s_own, sub + q, 32);
            float4 hv = *(const float4*)&h[(size_t)s * 128 + jj * 4];
            acc.x += a * hv.x; acc.y += a * hv.y;
            acc.z += a * hv.z; acc.w += a * hv.w;
        }
    }
    den += __shfl_xor(den, 1, 32);
    den += __shfl_xor(den, 2, 32);
    den += __shfl_xor(den, 4, 32);
    const float rcp = 1.f / (den + 1e-16f);
    float4 bv = *(const float4*)&b[jj * 4];
    float4 ov;
    ov.x = fmaxf(acc.x * rcp + bv.x, 0.f);
    ov.y = fmaxf(acc.y * rcp + bv.y, 0.f);
    ov.z = fmaxf(acc.z * rcp + bv.z, 0.f);
    ov.w = fmaxf(acc.w * rcp + bv.w, 0.f);
    *(float4*)&o[(size_t)d * 128 + jj * 4] = ov;
}

// ---------------- layer-2 gather: 4 dsts per 32-lane group (8 lanes x float4 each),
// 32 dsts per block. Same single-pass structure, H=1.
__global__ __launch_bounds__(256) void gather2_k(
    const int* __restrict__ rs, const int* __restrict__ csr,
    const float* __restrict__ as_, const float* __restrict__ ad_,
    const float* __restrict__ h, const float* __restrict__ b,
    float* __restrict__ o, int N) {
    const int jj = threadIdx.x & 31;
    const int es = jj & 7;              // edge slot AND channel group
    const int sub = jj & 24;            // subgroup base (one dst per subgroup)
    const int d = blockIdx.x * 32 + (threadIdx.x >> 5) * 4 + (jj >> 3);
    if (d >= N) return;
    const int beg = rs[d], end = rs[d + 1];
    const float adv = ad_[d];

    float4 acc = make_float4(0.f, 0.f, 0.f, 0.f);
    float den = 0.f;
    int j0 = beg;
    for (; j0 + 8 <= end; j0 += 8) {
        int s_own = csr[j0 + es];
        float e = lrelu(as_[s_own] + adv);
        float ex = __expf(fminf(e, 80.f));
        den += ex;
#pragma unroll
        for (int q = 0; q < 8; q++) {
            float a = __shfl(ex, sub + q, 32);
            int s = __shfl(s_own, sub + q, 32);
            float4 hv = *(const float4*)&h[(size_t)s * 32 + es * 4];
            acc.x += a * hv.x; acc.y += a * hv.y;
            acc.z += a * hv.z; acc.w += a * hv.w;
        }
    }
    int r = end - j0;
    if (r > 0) {
        int s_own = 0; float ex = 0.f;
        if (es < r) {
            s_own = csr[j0 + es];
            float e = lrelu(as_[s_own] + adv);
            ex = __expf(fminf(e, 80.f));
        }
        den += ex;
        for (int q = 0; q < r; q++) {
            float a = __shfl(ex, sub + q, 32);
            int s = __shfl(s_own, sub + q, 32);
            float4 hv = *(const float4*)&h[(size_t)s * 32 + es * 4];
            acc.x += a * hv.x; acc.y += a * hv.y;
            acc.z += a * hv.z; acc.w += a * hv.w;
        }
    }
    den += __shfl_xor(den, 1, 32);
    den += __shfl_xor(den, 2, 32);
    den += __shfl_xor(den, 4, 32);
    const float rcp = 1.f / (den + 1e-16f);
    float4 bv = *(const float4*)&b[es * 4];
    float4 ov;
    ov.x = acc.x * rcp + bv.x;
    ov.y = acc.y * rcp + bv.y;
    ov.z = acc.z * rcp + bv.z;
    ov.w = acc.w * rcp + bv.w;
    *(float4*)&o[(size_t)d * 32 + es * 4] = ov;
}

extern "C" void kernel_launch(void* const* d_in, const int* in_sizes, int n_in,
                              void* d_out, int out_size, void* d_ws, size_t ws_size,
                              hipStream_t stream) {
    const float* x    = (const float*)d_in[0];
    const int*   ei   = (const int*)d_in[1];
    const float* W1   = (const float*)d_in[2];
    const float* as1v = (const float*)d_in[3];
    const float* ad1v = (const float*)d_in[4];
    const float* b1   = (const float*)d_in[5];
    const float* W2   = (const float*)d_in[6];
    const float* as2v = (const float*)d_in[7];
    const float* ad2v = (const float*)d_in[8];
    const float* b2   = (const float*)d_in[9];
    float* out = (float*)d_out;

    const int N = in_sizes[0] / 128;
    const int E = in_sizes[1] / 2;
    const int EN = E + N;
    const int B = (N + 255) / 256;   // scan chunks (must be <= 1024)

    // workspace layout
    char* base = (char*)d_ws;
    size_t o = 0;
    auto alloc = [&](size_t bytes) { void* p = base + o; o += (bytes + 255) & ~(size_t)255; return p; };
    float* h1   = (float*)alloc((size_t)N * 128 * 4);
    float* h2   = (float*)alloc((size_t)N * 32 * 4);
    float* as1  = (float*)alloc((size_t)N * 4 * 4);
    float* ad1  = (float*)alloc((size_t)N * 4 * 4);
    float* as2  = (float*)alloc((size_t)N * 4);
    float* ad2  = (float*)alloc((size_t)N * 4);
    int*   deg  = (int*)alloc((size_t)N * 4);
    int*   tmp  = (int*)alloc((size_t)N * 4);
    int*   part = (int*)alloc((size_t)1024 * 4);
    int*   rs   = (int*)alloc((size_t)(N + 1) * 4);
    int*   cur  = (int*)alloc((size_t)N * 4);
    int*   csr  = (int*)alloc((size_t)EN * 4);
    float* o1   = (float*)alloc((size_t)N * 128 * 4);

    hipMemsetAsync(deg, 0, (size_t)N * 4, stream);

    const int nbE = (EN + 255) / 256;
    const int nbN = (N + 255) / 256;
    const int nbG = (N + 63) / 64;

    // ---- layer-1 GEMM + CSR build (shared by both layers)
    gemm1_att<<<nbG, 256, 0, stream>>>(x, W1, as1v, ad1v, h1, as1, ad1, N);
    hist_k<<<nbE, 256, 0, stream>>>(ei, E, N, deg);
    scan1_k<<<nbN, 256, 0, stream>>>(deg, tmp, part, N);
    scan2_k<<<1, 1024, 0, stream>>>(part, B);
    scan3_k<<<nbN, 256, 0, stream>>>(tmp, part, deg, rs, cur, N);
    scatter_k<<<nbE, 256, 0, stream>>>(ei, E, N, cur, csr);

    // ---- layer 1 edge softmax + aggregate + bias + relu -> o1
    gather1_k<<<(N + 7) / 8, 256, 0, stream>>>(rs, csr, as1, ad1, h1, b1, o1, N);

    // ---- layer 2
    gemm2_att<<<nbG, 256, 0, stream>>>(o1, W2, as2v, ad2v, h2, as2, ad2, N);
    gather2_k<<<(N + 31) / 32, 256, 0, stream>>>(rs, csr, as2, ad2, h2, b2, out, N);
}

// Round 5
// 490.658 us; speedup vs baseline: 3.2369x; 1.2134x over previous
//
#include <hip/hip_runtime.h>
#include <hip/hip_bf16.h>

// GAT 2-layer, fp32 compute / bf16 h-payload. N=100000, L1: H=4,C=32; L2: H=1,C=32.
//
// R1: CSR gather instead of float-atomic scatter (1588 -> 826 us).
// R2: cooperative softmax via shfl broadcast (826 -> 734).
// R3: single-pass softmax (exp clamp 80), float4 loads, 8-deep unroll (734 -> 595).
// R4: (a) scatter_k made atomic-free (rank precomputed in hist) -> fire-and-forget
//     stores; (b) h payload packed bf16 (RTNE) halving gather traffic; gather1
//     restructured to 16 lanes/dst, 16B loads, 16-edge chunks (16 loads in flight).
// Self-loops are implicit: edge ids >= E map to (n,n).

__device__ __forceinline__ float lrelu(float v) { return v >= 0.f ? v : 0.2f * v; }

__device__ __forceinline__ unsigned f2bf(float f) {   // RTNE f32->bf16 (finite inputs)
    unsigned u = __float_as_uint(f);
    return (u + 0x7FFFu + ((u >> 16) & 1u)) >> 16;
}

__device__ __forceinline__ void bf16x8_fma(uint4 hv, float a, float* acc) {
    acc[0] = fmaf(a, __uint_as_float(hv.x << 16), acc[0]);
    acc[1] = fmaf(a, __uint_as_float(hv.x & 0xFFFF0000u), acc[1]);
    acc[2] = fmaf(a, __uint_as_float(hv.y << 16), acc[2]);
    acc[3] = fmaf(a, __uint_as_float(hv.y & 0xFFFF0000u), acc[3]);
    acc[4] = fmaf(a, __uint_as_float(hv.z << 16), acc[4]);
    acc[5] = fmaf(a, __uint_as_float(hv.z & 0xFFFF0000u), acc[5]);
    acc[6] = fmaf(a, __uint_as_float(hv.w << 16), acc[6]);
    acc[7] = fmaf(a, __uint_as_float(hv.w & 0xFFFF0000u), acc[7]);
}

// ---------------- GEMM1: x[N,128] @ W[128,128] -> h(bf16)[N,128]; fused a_src/a_dst
__global__ __launch_bounds__(256) void gemm1_att(
    const float* __restrict__ x, const float* __restrict__ W,
    const float* __restrict__ atts, const float* __restrict__ attd,
    uint2* __restrict__ h, float* __restrict__ as_, float* __restrict__ ad_, int N) {
    __shared__ float xs[64][33];
    __shared__ float ws[32][132];
    const int t = threadIdx.x;
    const int n0 = blockIdx.x * 64;
    const int tcol = t & 31;
    const int trow = t >> 5;
    float acc[8][4];
#pragma unroll
    for (int i = 0; i < 8; i++) { acc[i][0]=0.f; acc[i][1]=0.f; acc[i][2]=0.f; acc[i][3]=0.f; }

    for (int k0 = 0; k0 < 128; k0 += 32) {
        {
            int k = t & 31, r0 = t >> 5;
#pragma unroll
            for (int i = 0; i < 8; i++) {
                int r = r0 + i * 8;
                int n = n0 + r;
                xs[r][k] = (n < N) ? x[(size_t)n * 128 + k0 + k] : 0.f;
            }
        }
        {
            int c = t & 127, kk = t >> 7;
#pragma unroll
            for (int i = 0; i < 16; i++) {
                int k = kk + i * 2;
                ws[k][c] = W[(k0 + k) * 128 + c];
            }
        }
        __syncthreads();
#pragma unroll
        for (int k = 0; k < 32; k++) {
            float4 wv = *(const float4*)&ws[k][tcol * 4];
#pragma unroll
            for (int i = 0; i < 8; i++) {
                float xv = xs[trow * 8 + i][k];
                acc[i][0] += xv * wv.x; acc[i][1] += xv * wv.y;
                acc[i][2] += xv * wv.z; acc[i][3] += xv * wv.w;
            }
        }
        __syncthreads();
    }

    const int head = tcol >> 3;
    const int cbase = tcol * 4;
    const int csub = cbase - head * 32;
    float s0 = atts[head * 32 + csub + 0], s1 = atts[head * 32 + csub + 1],
          s2 = atts[head * 32 + csub + 2], s3 = atts[head * 32 + csub + 3];
    float d0 = attd[head * 32 + csub + 0], d1 = attd[head * 32 + csub + 1],
          d2 = attd[head * 32 + csub + 2], d3 = attd[head * 32 + csub + 3];
#pragma unroll
    for (int i = 0; i < 8; i++) {
        int n = n0 + trow * 8 + i;
        if (n < N) {
            uint2 pk;
            pk.x = f2bf(acc[i][0]) | (f2bf(acc[i][1]) << 16);
            pk.y = f2bf(acc[i][2]) | (f2bf(acc[i][3]) << 16);
            h[(size_t)n * 32 + tcol] = pk;
            float ps = acc[i][0]*s0 + acc[i][1]*s1 + acc[i][2]*s2 + acc[i][3]*s3;
            float pd = acc[i][0]*d0 + acc[i][1]*d1 + acc[i][2]*d2 + acc[i][3]*d3;
            ps += __shfl_xor(ps, 1); pd += __shfl_xor(pd, 1);
            ps += __shfl_xor(ps, 2); pd += __shfl_xor(pd, 2);
            ps += __shfl_xor(ps, 4); pd += __shfl_xor(pd, 4);
            if ((tcol & 7) == 0) { as_[n * 4 + head] = ps; ad_[n * 4 + head] = pd; }
        }
    }
}

// ---------------- GEMM2: o1[N,128] @ W2[128,32] -> h2(bf16)[N,32]; fused a_src/a_dst
__global__ __launch_bounds__(256) void gemm2_att(
    const float* __restrict__ x, const float* __restrict__ W,
    const float* __restrict__ atts, const float* __restrict__ attd,
    unsigned* __restrict__ h, float* __restrict__ as_, float* __restrict__ ad_, int N) {
    __shared__ float xs[64][33];
    __shared__ float ws[32][33];
    const int t = threadIdx.x;
    const int n0 = blockIdx.x * 64;
    const int tcol = t & 31;
    const int trow = t >> 5;
    float acc[8];
#pragma unroll
    for (int i = 0; i < 8; i++) acc[i] = 0.f;

    for (int k0 = 0; k0 < 128; k0 += 32) {
        {
            int k = t & 31, r0 = t >> 5;
#pragma unroll
            for (int i = 0; i < 8; i++) {
                int r = r0 + i * 8;
                int n = n0 + r;
                xs[r][k] = (n < N) ? x[(size_t)n * 128 + k0 + k] : 0.f;
            }
        }
        {
            int c = t & 31, kk = t >> 5;
#pragma unroll
            for (int i = 0; i < 4; i++) {
                int k = kk + i * 8;
                ws[k][c] = W[(k0 + k) * 32 + c];
            }
        }
        __syncthreads();
#pragma unroll
        for (int k = 0; k < 32; k++) {
            float wv = ws[k][tcol];
#pragma unroll
            for (int i = 0; i < 8; i++) acc[i] += xs[trow * 8 + i][k] * wv;
        }
        __syncthreads();
    }

    float sa = atts[tcol], da = attd[tcol];
#pragma unroll
    for (int i = 0; i < 8; i++) {
        int n = n0 + trow * 8 + i;
        if (n < N) {
            float hi = __shfl_xor(acc[i], 1);
            if ((tcol & 1) == 0)
                h[(size_t)n * 16 + (tcol >> 1)] = f2bf(acc[i]) | (f2bf(hi) << 16);
            float ps = acc[i] * sa;
            float pd = acc[i] * da;
#pragma unroll
            for (int m = 1; m < 32; m <<= 1) { ps += __shfl_xor(ps, m); pd += __shfl_xor(pd, m); }
            if (tcol == 0) { as_[n] = ps; ad_[n] = pd; }
        }
    }
}

// ---------------- CSR build: hist+rank -> scan -> atomic-free scatter -------
__global__ __launch_bounds__(256) void hist_rank_k(const int* __restrict__ ei, int E, int N,
                                                   int* __restrict__ deg, int* __restrict__ rank) {
    int e = blockIdx.x * 256 + threadIdx.x;
    if (e >= E + N) return;
    int d = (e < E) ? ei[E + e] : e - E;
    rank[e] = atomicAdd(&deg[d], 1);
}

__global__ __launch_bounds__(256) void scan1_k(const int* __restrict__ deg,
                                               int* __restrict__ tmp, int* __restrict__ partial, int N) {
    __shared__ int sh[256];
    int i = blockIdx.x * 256 + threadIdx.x;
    int v = (i < N) ? deg[i] : 0;
    sh[threadIdx.x] = v;
    __syncthreads();
#pragma unroll
    for (int off = 1; off < 256; off <<= 1) {
        int t = (threadIdx.x >= off) ? sh[threadIdx.x - off] : 0;
        __syncthreads();
        sh[threadIdx.x] += t;
        __syncthreads();
    }
    if (i < N) tmp[i] = sh[threadIdx.x];
    if (threadIdx.x == 255) partial[blockIdx.x] = sh[255];
}

__global__ __launch_bounds__(1024) void scan2_k(int* __restrict__ partial, int B) {
    __shared__ int sh[1024];
    int i = threadIdx.x;
    int v = (i < B) ? partial[i] : 0;
    sh[i] = v;
    __syncthreads();
#pragma unroll
    for (int off = 1; off < 1024; off <<= 1) {
        int t = (i >= off) ? sh[i - off] : 0;
        __syncthreads();
        sh[i] += t;
        __syncthreads();
    }
    if (i < B) partial[i] = sh[i] - v;   // exclusive
}

__global__ __launch_bounds__(256) void scan3_k(const int* __restrict__ tmp, const int* __restrict__ partial,
                                               int* __restrict__ rs, int N) {
    int i = blockIdx.x * 256 + threadIdx.x;
    if (i < N) rs[i + 1] = tmp[i] + partial[blockIdx.x];
    if (i == 0) rs[0] = 0;
}

__global__ __launch_bounds__(256) void scatter_k(const int* __restrict__ ei, const int* __restrict__ rank,
                                                 const int* __restrict__ rs, int E, int N,
                                                 int* __restrict__ csr) {
    int e = blockIdx.x * 256 + threadIdx.x;
    if (e >= E + N) return;
    int s, d;
    if (e < E) { s = ei[e]; d = ei[E + e]; } else { s = e - E; d = s; }
    csr[rs[d] + rank[e]] = s;      // fire-and-forget random store
}

// ---------------- layer-1 gather: 16 lanes/dst, 8 bf16 ch/lane (uint4 loads),
// 16-edge chunks fully unrolled (16 loads in flight). Lane l (0..15): channels
// 8l..8l+7 (head l>>2); owns softmax terms for (slot (l&3)+4k, head l>>2).
__global__ __launch_bounds__(256) void gather1_k(
    const int* __restrict__ rs, const int* __restrict__ csr,
    const float* __restrict__ as_, const float* __restrict__ ad_,
    const uint4* __restrict__ h, const float* __restrict__ b,
    float* __restrict__ o, int N) {
    const int jj = threadIdx.x & 31;
    const int l16 = jj & 15;
    const int sub = jj & 16;             // 16-lane subgroup base in 32-window
    const int d = blockIdx.x * 16 + (threadIdx.x >> 5) * 2 + (jj >> 4);
    if (d >= N) return;
    const int hl = l16 >> 2;             // my head
    const int sl = l16 & 3;              // my slot base
    const int beg = rs[d], end = rs[d + 1];
    const float adv = ad_[d * 4 + hl];

    float acc[8];
#pragma unroll
    for (int i = 0; i < 8; i++) acc[i] = 0.f;
    float den = 0.f;

    int j0 = beg;
    for (; j0 + 16 <= end; j0 += 16) {
        int sv0 = csr[j0 + sl];
        int sv1 = csr[j0 + sl + 4];
        int sv2 = csr[j0 + sl + 8];
        int sv3 = csr[j0 + sl + 12];
        float ex0 = __expf(fminf(lrelu(as_[sv0 * 4 + hl] + adv), 80.f));
        float ex1 = __expf(fminf(lrelu(as_[sv1 * 4 + hl] + adv), 80.f));
        float ex2 = __expf(fminf(lrelu(as_[sv2 * 4 + hl] + adv), 80.f));
        float ex3 = __expf(fminf(lrelu(as_[sv3 * 4 + hl] + adv), 80.f));
        den += ex0 + ex1 + ex2 + ex3;
#pragma unroll
        for (int k = 0; k < 4; k++) {
            float exk = (k == 0) ? ex0 : (k == 1) ? ex1 : (k == 2) ? ex2 : ex3;
            int   svk = (k == 0) ? sv0 : (k == 1) ? sv1 : (k == 2) ? sv2 : sv3;
#pragma unroll
            for (int q = 0; q < 4; q++) {
                int src = sub + (l16 & 12) + q;
                float a = __shfl(exk, src, 32);
                int   s = __shfl(svk, src, 32);
                uint4 hv = h[(size_t)s * 16 + l16];
                bf16x8_fma(hv, a, acc);
            }
        }
    }
    int r = end - j0;
    if (r > 0) {
        float exs[4] = {0.f, 0.f, 0.f, 0.f};
        int   svs[4] = {0, 0, 0, 0};
#pragma unroll
        for (int k = 0; k < 4; k++) {
            int slot = sl + 4 * k;
            if (slot < r) {
                int s = csr[j0 + slot];
                svs[k] = s;
                exs[k] = __expf(fminf(lrelu(as_[s * 4 + hl] + adv), 80.f));
                den += exs[k];
            }
        }
        for (int e = 0; e < r; e++) {
            int k = e >> 2, q = e & 3;
            float exk = (k == 0) ? exs[0] : (k == 1) ? exs[1] : (k == 2) ? exs[2] : exs[3];
            int   svk = (k == 0) ? svs[0] : (k == 1) ? svs[1] : (k == 2) ? svs[2] : svs[3];
            int src = sub + (l16 & 12) + q;
            float a = __shfl(exk, src, 32);
            int   s = __shfl(svk, src, 32);
            uint4 hv = h[(size_t)s * 16 + l16];
            bf16x8_fma(hv, a, acc);
        }
    }
    // den: sum the 4 slot-lanes of my head (xor 1,2 stays in the 4-lane head group)
    den += __shfl_xor(den, 1, 32);
    den += __shfl_xor(den, 2, 32);
    const float rcp = 1.f / (den + 1e-16f);
    float4 b0 = *(const float4*)&b[l16 * 8];
    float4 b1 = *(const float4*)&b[l16 * 8 + 4];
    float4 o0, o1v;
    o0.x  = fmaxf(acc[0] * rcp + b0.x, 0.f);
    o0.y  = fmaxf(acc[1] * rcp + b0.y, 0.f);
    o0.z  = fmaxf(acc[2] * rcp + b0.z, 0.f);
    o0.w  = fmaxf(acc[3] * rcp + b0.w, 0.f);
    o1v.x = fmaxf(acc[4] * rcp + b1.x, 0.f);
    o1v.y = fmaxf(acc[5] * rcp + b1.y, 0.f);
    o1v.z = fmaxf(acc[6] * rcp + b1.z, 0.f);
    o1v.w = fmaxf(acc[7] * rcp + b1.w, 0.f);
    *(float4*)&o[(size_t)d * 128 + l16 * 8]     = o0;
    *(float4*)&o[(size_t)d * 128 + l16 * 8 + 4] = o1v;
}

// ---------------- layer-2 gather: 4 lanes/dst, 8 bf16 ch/lane, 16-edge chunks.
__global__ __launch_bounds__(256) void gather2_k(
    const int* __restrict__ rs, const int* __restrict__ csr,
    const float* __restrict__ as_, const float* __restrict__ ad_,
    const uint4* __restrict__ h, const float* __restrict__ b,
    float* __restrict__ o, int N) {
    const int jj = threadIdx.x & 31;
    const int l4 = jj & 3;
    const int sub = jj & 28;             // 4-lane subgroup base
    const int d = blockIdx.x * 64 + (threadIdx.x >> 5) * 8 + (jj >> 2);
    if (d >= N) return;
    const int beg = rs[d], end = rs[d + 1];
    const float adv = ad_[d];

    float acc[8];
#pragma unroll
    for (int i = 0; i < 8; i++) acc[i] = 0.f;
    float den = 0.f;

    int j0 = beg;
    for (; j0 + 16 <= end; j0 += 16) {
        int sv0 = csr[j0 + l4];
        int sv1 = csr[j0 + l4 + 4];
        int sv2 = csr[j0 + l4 + 8];
        int sv3 = csr[j0 + l4 + 12];
        float ex0 = __expf(fminf(lrelu(as_[sv0] + adv), 80.f));
        float ex1 = __expf(fminf(lrelu(as_[sv1] + adv), 80.f));
        float ex2 = __expf(fminf(lrelu(as_[sv2] + adv), 80.f));
        float ex3 = __expf(fminf(lrelu(as_[sv3] + adv), 80.f));
        den += ex0 + ex1 + ex2 + ex3;
#pragma unroll
        for (int k = 0; k < 4; k++) {
            float exk = (k == 0) ? ex0 : (k == 1) ? ex1 : (k == 2) ? ex2 : ex3;
            int   svk = (k == 0) ? sv0 : (k == 1) ? sv1 : (k == 2) ? sv2 : sv3;
#pragma unroll
            for (int q = 0; q < 4; q++) {
                int src = sub + q;
                float a = __shfl(exk, src, 32);
                int   s = __shfl(svk, src, 32);
                uint4 hv = h[(size_t)s * 4 + l4];
                bf16x8_fma(hv, a, acc);
            }
        }
    }
    int r = end - j0;
    if (r > 0) {
        float exs[4] = {0.f, 0.f, 0.f, 0.f};
        int   svs[4] = {0, 0, 0, 0};
#pragma unroll
        for (int k = 0; k < 4; k++) {
            int slot = l4 + 4 * k;
            if (slot < r) {
                int s = csr[j0 + slot];
                svs[k] = s;
                exs[k] = __expf(fminf(lrelu(as_[s] + adv), 80.f));
                den += exs[k];
            }
        }
        for (int e = 0; e < r; e++) {
            int k = e >> 2, q = e & 3;
            float exk = (k == 0) ? exs[0] : (k == 1) ? exs[1] : (k == 2) ? exs[2] : exs[3];
            int   svk = (k == 0) ? svs[0] : (k == 1) ? svs[1] : (k == 2) ? svs[2] : svs[3];
            int src = sub + q;
            float a = __shfl(exk, src, 32);
            int   s = __shfl(svk, src, 32);
            uint4 hv = h[(size_t)s * 4 + l4];
            bf16x8_fma(hv, a, acc);
        }
    }
    den += __shfl_xor(den, 1, 32);
    den += __shfl_xor(den, 2, 32);
    const float rcp = 1.f / (den + 1e-16f);
    float4 b0 = *(const float4*)&b[l4 * 8];
    float4 b1 = *(const float4*)&b[l4 * 8 + 4];
    float4 o0, o1v;
    o0.x  = acc[0] * rcp + b0.x;
    o0.y  = acc[1] * rcp + b0.y;
    o0.z  = acc[2] * rcp + b0.z;
    o0.w  = acc[3] * rcp + b0.w;
    o1v.x = acc[4] * rcp + b1.x;
    o1v.y = acc[5] * rcp + b1.y;
    o1v.z = acc[6] * rcp + b1.z;
    o1v.w = acc[7] * rcp + b1.w;
    *(float4*)&o[(size_t)d * 32 + l4 * 8]     = o0;
    *(float4*)&o[(size_t)d * 32 + l4 * 8 + 4] = o1v;
}

extern "C" void kernel_launch(void* const* d_in, const int* in_sizes, int n_in,
                              void* d_out, int out_size, void* d_ws, size_t ws_size,
                              hipStream_t stream) {
    const float* x    = (const float*)d_in[0];
    const int*   ei   = (const int*)d_in[1];
    const float* W1   = (const float*)d_in[2];
    const float* as1v = (const float*)d_in[3];
    const float* ad1v = (const float*)d_in[4];
    const float* b1   = (const float*)d_in[5];
    const float* W2   = (const float*)d_in[6];
    const float* as2v = (const float*)d_in[7];
    const float* ad2v = (const float*)d_in[8];
    const float* b2   = (const float*)d_in[9];
    float* out = (float*)d_out;

    const int N = in_sizes[0] / 128;
    const int E = in_sizes[1] / 2;
    const int EN = E + N;
    const int B = (N + 255) / 256;   // scan chunks (must be <= 1024)

    // workspace layout
    char* base = (char*)d_ws;
    size_t o = 0;
    auto alloc = [&](size_t bytes) { void* p = base + o; o += (bytes + 255) & ~(size_t)255; return p; };
    uint2*    h1   = (uint2*)alloc((size_t)N * 128 * 2);     // bf16 h1
    unsigned* h2   = (unsigned*)alloc((size_t)N * 32 * 2);   // bf16 h2
    float*    as1  = (float*)alloc((size_t)N * 4 * 4);
    float*    ad1  = (float*)alloc((size_t)N * 4 * 4);
    float*    as2  = (float*)alloc((size_t)N * 4);
    float*    ad2  = (float*)alloc((size_t)N * 4);
    int*      deg  = (int*)alloc((size_t)N * 4);
    int*      tmp  = (int*)alloc((size_t)N * 4);
    int*      part = (int*)alloc((size_t)1024 * 4);
    int*      rs   = (int*)alloc((size_t)(N + 1) * 4);
    int*      rank = (int*)alloc((size_t)EN * 4);
    int*      csr  = (int*)alloc((size_t)EN * 4);
    float*    o1   = (float*)alloc((size_t)N * 128 * 4);

    hipMemsetAsync(deg, 0, (size_t)N * 4, stream);

    const int nbE = (EN + 255) / 256;
    const int nbN = (N + 255) / 256;
    const int nbG = (N + 63) / 64;

    // ---- layer-1 GEMM + CSR build (shared by both layers)
    gemm1_att<<<nbG, 256, 0, stream>>>(x, W1, as1v, ad1v, h1, as1, ad1, N);
    hist_rank_k<<<nbE, 256, 0, stream>>>(ei, E, N, deg, rank);
    scan1_k<<<nbN, 256, 0, stream>>>(deg, tmp, part, N);
    scan2_k<<<1, 1024, 0, stream>>>(part, B);
    scan3_k<<<nbN, 256, 0, stream>>>(tmp, part, rs, N);
    scatter_k<<<nbE, 256, 0, stream>>>(ei, rank, rs, E, N, csr);

    // ---- layer 1 edge softmax + aggregate + bias + relu -> o1
    gather1_k<<<(N + 15) / 16, 256, 0, stream>>>(rs, csr, as1, ad1, (const uint4*)h1, b1, o1, N);

    // ---- layer 2
    gemm2_att<<<nbG, 256, 0, stream>>>(o1, W2, as2v, ad2v, h2, as2, ad2, N);
    gather2_k<<<(N + 63) / 64, 256, 0, stream>>>(rs, csr, as2, ad2, (const uint4*)h2, b2, out, N);
}

// Round 6
// 442.944 us; speedup vs baseline: 3.5855x; 1.1077x over previous
//
#include <hip/hip_runtime.h>
#include <hip/hip_bf16.h>

// GAT 2-layer. N=100000, L1: H=4,C=32 (HC=128), L2: H=1,C=32.
//
// R1: CSR gather instead of float-atomic scatter (1588 -> 826 us).
// R2: cooperative softmax via shfl broadcast (826 -> 734).
// R3: single-pass softmax, float4 loads, 8-deep unroll (734 -> 595).
// R4: atomic-free scatter; bf16 h payload; 16-deep unroll (595 -> 491).
// R5: both GEMMs -> bf16 MFMA (16x16x32), zero LDS / zero barriers:
//     A (row-major) and B^T loaded as lane-contiguous uint4 frags, att
//     logits fused in epilogue via 16-lane shfl reduce. x/W1/W2 cast to
//     bf16 (W transposed) by tiny kernels. gather1 emits o1 as bf16.
// Self-loops are implicit: edge ids >= E map to (n,n).

typedef __bf16 bf16x8 __attribute__((ext_vector_type(8)));
typedef float f32x4 __attribute__((ext_vector_type(4)));

__device__ __forceinline__ float lrelu(float v) { return v >= 0.f ? v : 0.2f * v; }

__device__ __forceinline__ unsigned f2bf(float f) {   // RTNE f32->bf16 (finite inputs)
    unsigned u = __float_as_uint(f);
    return (u + 0x7FFFu + ((u >> 16) & 1u)) >> 16;
}

__device__ __forceinline__ bf16x8 as_bf16x8(uint4 u) {
    union { uint4 u; bf16x8 b; } c; c.u = u; return c.b;
}

__device__ __forceinline__ void bf16x8_fma(uint4 hv, float a, float* acc) {
    acc[0] = fmaf(a, __uint_as_float(hv.x << 16), acc[0]);
    acc[1] = fmaf(a, __uint_as_float(hv.x & 0xFFFF0000u), acc[1]);
    acc[2] = fmaf(a, __uint_as_float(hv.y << 16), acc[2]);
    acc[3] = fmaf(a, __uint_as_float(hv.y & 0xFFFF0000u), acc[3]);
    acc[4] = fmaf(a, __uint_as_float(hv.z << 16), acc[4]);
    acc[5] = fmaf(a, __uint_as_float(hv.z & 0xFFFF0000u), acc[5]);
    acc[6] = fmaf(a, __uint_as_float(hv.w << 16), acc[6]);
    acc[7] = fmaf(a, __uint_as_float(hv.w & 0xFFFF0000u), acc[7]);
}

// ---------------- casts -----------------------------------------------------
__global__ __launch_bounds__(256) void cast_x_k(const float* __restrict__ x,
                                                ushort* __restrict__ xb, long long n8) {
    long long i = (long long)blockIdx.x * 256 + threadIdx.x;
    if (i >= n8) return;
    const float4* p = (const float4*)(x + i * 8);
    float4 a = p[0], c = p[1];
    uint4 o;
    o.x = f2bf(a.x) | (f2bf(a.y) << 16);
    o.y = f2bf(a.z) | (f2bf(a.w) << 16);
    o.z = f2bf(c.x) | (f2bf(c.y) << 16);
    o.w = f2bf(c.z) | (f2bf(c.w) << 16);
    ((uint4*)xb)[i] = o;
}

// W1[128,128] -> w1t[c][k] bf16 ; W2[128,32] -> w2t[c][k] bf16
__global__ __launch_bounds__(256) void cast_w_k(const float* __restrict__ W1,
                                                const float* __restrict__ W2,
                                                ushort* __restrict__ w1t,
                                                ushort* __restrict__ w2t) {
    int tid = blockIdx.x * 256 + threadIdx.x;
    if (tid < 16384) {
        int k = tid >> 7, c = tid & 127;
        w1t[c * 128 + k] = (ushort)f2bf(W1[tid]);
    }
    if (tid < 4096) {
        int k = tid >> 5, c = tid & 31;
        w2t[c * 128 + k] = (ushort)f2bf(W2[tid]);
    }
}

// ---------------- GEMM1 (MFMA): xb[N,128]bf16 @ W1 -> h[N,128]bf16 + as/ad --
// Block: 64 rows, 4 waves x 16 rows. 8 col-tiles, K=128 in 4 steps. No LDS.
__global__ __launch_bounds__(256) void gemm1_mfma(
    const ushort* __restrict__ xb, const ushort* __restrict__ w1t,
    const float* __restrict__ atts, const float* __restrict__ attd,
    ushort* __restrict__ h, float* __restrict__ as_, float* __restrict__ ad_, int N) {
    const int w = threadIdx.x >> 6;
    const int l = threadIdx.x & 63;
    const int c15 = l & 15;
    const int quad = l >> 4;
    const int n_base = blockIdx.x * 64 + w * 16;
    const int n = n_base + c15;

    bf16x8 a[4];
    if (n < N) {
        const uint4* xr = (const uint4*)(xb + (size_t)n * 128);
#pragma unroll
        for (int ks = 0; ks < 4; ks++) a[ks] = as_bf16x8(xr[ks * 4 + quad]);
    } else {
        uint4 z = make_uint4(0, 0, 0, 0);
#pragma unroll
        for (int ks = 0; ks < 4; ks++) a[ks] = as_bf16x8(z);
    }

    f32x4 acc[8];
#pragma unroll
    for (int ct = 0; ct < 8; ct++) acc[ct] = (f32x4){0.f, 0.f, 0.f, 0.f};

#pragma unroll
    for (int ct = 0; ct < 8; ct++) {
        const uint4* wr = (const uint4*)(w1t + (size_t)(ct * 16 + c15) * 128);
#pragma unroll
        for (int ks = 0; ks < 4; ks++) {
            bf16x8 bfrag = as_bf16x8(wr[ks * 4 + quad]);
            acc[ct] = __builtin_amdgcn_mfma_f32_16x16x32_bf16(a[ks], bfrag, acc[ct], 0, 0, 0);
        }
    }

    // h stores: lane holds col=ct*16+c15, rows n_base+quad*4+reg
#pragma unroll
    for (int ct = 0; ct < 8; ct++) {
        int col = ct * 16 + c15;
#pragma unroll
        for (int reg = 0; reg < 4; reg++) {
            int n_out = n_base + quad * 4 + reg;
            if (n_out < N) h[(size_t)n_out * 128 + col] = (ushort)f2bf(acc[ct][reg]);
        }
    }
    // attention logits per head (cols of head hh live in tiles 2hh, 2hh+1)
#pragma unroll
    for (int hh = 0; hh < 4; hh++) {
        float sA = atts[hh * 32 + c15], sB = atts[hh * 32 + 16 + c15];
        float dA = attd[hh * 32 + c15], dB = attd[hh * 32 + 16 + c15];
#pragma unroll
        for (int reg = 0; reg < 4; reg++) {
            float ps = acc[2 * hh][reg] * sA + acc[2 * hh + 1][reg] * sB;
            float pd = acc[2 * hh][reg] * dA + acc[2 * hh + 1][reg] * dB;
            ps += __shfl_xor(ps, 1); pd += __shfl_xor(pd, 1);
            ps += __shfl_xor(ps, 2); pd += __shfl_xor(pd, 2);
            ps += __shfl_xor(ps, 4); pd += __shfl_xor(pd, 4);
            ps += __shfl_xor(ps, 8); pd += __shfl_xor(pd, 8);
            int n_out = n_base + quad * 4 + reg;
            if (c15 == 0 && n_out < N) { as_[n_out * 4 + hh] = ps; ad_[n_out * 4 + hh] = pd; }
        }
    }
}

// ---------------- GEMM2 (MFMA): o1[N,128]bf16 @ W2 -> h2[N,32]bf16 + as/ad --
__global__ __launch_bounds__(256) void gemm2_mfma(
    const ushort* __restrict__ ob, const ushort* __restrict__ w2t,
    const float* __restrict__ atts, const float* __restrict__ attd,
    ushort* __restrict__ h, float* __restrict__ as_, float* __restrict__ ad_, int N) {
    const int w = threadIdx.x >> 6;
    const int l = threadIdx.x & 63;
    const int c15 = l & 15;
    const int quad = l >> 4;
    const int n_base = blockIdx.x * 64 + w * 16;
    const int n = n_base + c15;

    bf16x8 a[4];
    if (n < N) {
        const uint4* xr = (const uint4*)(ob + (size_t)n * 128);
#pragma unroll
        for (int ks = 0; ks < 4; ks++) a[ks] = as_bf16x8(xr[ks * 4 + quad]);
    } else {
        uint4 z = make_uint4(0, 0, 0, 0);
#pragma unroll
        for (int ks = 0; ks < 4; ks++) a[ks] = as_bf16x8(z);
    }

    f32x4 acc[2];
#pragma unroll
    for (int ct = 0; ct < 2; ct++) acc[ct] = (f32x4){0.f, 0.f, 0.f, 0.f};

#pragma unroll
    for (int ct = 0; ct < 2; ct++) {
        const uint4* wr = (const uint4*)(w2t + (size_t)(ct * 16 + c15) * 128);
#pragma unroll
        for (int ks = 0; ks < 4; ks++) {
            bf16x8 bfrag = as_bf16x8(wr[ks * 4 + quad]);
            acc[ct] = __builtin_amdgcn_mfma_f32_16x16x32_bf16(a[ks], bfrag, acc[ct], 0, 0, 0);
        }
    }

#pragma unroll
    for (int ct = 0; ct < 2; ct++) {
        int col = ct * 16 + c15;
#pragma unroll
        for (int reg = 0; reg < 4; reg++) {
            int n_out = n_base + quad * 4 + reg;
            if (n_out < N) h[(size_t)n_out * 32 + col] = (ushort)f2bf(acc[ct][reg]);
        }
    }
    float sA = atts[c15], sB = atts[16 + c15];
    float dA = attd[c15], dB = attd[16 + c15];
#pragma unroll
    for (int reg = 0; reg < 4; reg++) {
        float ps = acc[0][reg] * sA + acc[1][reg] * sB;
        float pd = acc[0][reg] * dA + acc[1][reg] * dB;
        ps += __shfl_xor(ps, 1); pd += __shfl_xor(pd, 1);
        ps += __shfl_xor(ps, 2); pd += __shfl_xor(pd, 2);
        ps += __shfl_xor(ps, 4); pd += __shfl_xor(pd, 4);
        ps += __shfl_xor(ps, 8); pd += __shfl_xor(pd, 8);
        int n_out = n_base + quad * 4 + reg;
        if (c15 == 0 && n_out < N) { as_[n_out] = ps; ad_[n_out] = pd; }
    }
}

// ---------------- CSR build: hist+rank -> scan -> atomic-free scatter -------
__global__ __launch_bounds__(256) void hist_rank_k(const int* __restrict__ ei, int E, int N,
                                                   int* __restrict__ deg, int* __restrict__ rank) {
    int e = blockIdx.x * 256 + threadIdx.x;
    if (e >= E + N) return;
    int d = (e < E) ? ei[E + e] : e - E;
    rank[e] = atomicAdd(&deg[d], 1);
}

__global__ __launch_bounds__(256) void scan1_k(const int* __restrict__ deg,
                                               int* __restrict__ tmp, int* __restrict__ partial, int N) {
    __shared__ int sh[256];
    int i = blockIdx.x * 256 + threadIdx.x;
    int v = (i < N) ? deg[i] : 0;
    sh[threadIdx.x] = v;
    __syncthreads();
#pragma unroll
    for (int off = 1; off < 256; off <<= 1) {
        int t = (threadIdx.x >= off) ? sh[threadIdx.x - off] : 0;
        __syncthreads();
        sh[threadIdx.x] += t;
        __syncthreads();
    }
    if (i < N) tmp[i] = sh[threadIdx.x];
    if (threadIdx.x == 255) partial[blockIdx.x] = sh[255];
}

__global__ __launch_bounds__(1024) void scan2_k(int* __restrict__ partial, int B) {
    __shared__ int sh[1024];
    int i = threadIdx.x;
    int v = (i < B) ? partial[i] : 0;
    sh[i] = v;
    __syncthreads();
#pragma unroll
    for (int off = 1; off < 1024; off <<= 1) {
        int t = (i >= off) ? sh[i - off] : 0;
        __syncthreads();
        sh[i] += t;
        __syncthreads();
    }
    if (i < B) partial[i] = sh[i] - v;   // exclusive
}

__global__ __launch_bounds__(256) void scan3_k(const int* __restrict__ tmp, const int* __restrict__ partial,
                                               int* __restrict__ rs, int N) {
    int i = blockIdx.x * 256 + threadIdx.x;
    if (i < N) rs[i + 1] = tmp[i] + partial[blockIdx.x];
    if (i == 0) rs[0] = 0;
}

__global__ __launch_bounds__(256) void scatter_k(const int* __restrict__ ei, const int* __restrict__ rank,
                                                 const int* __restrict__ rs, int E, int N,
                                                 int* __restrict__ csr) {
    int e = blockIdx.x * 256 + threadIdx.x;
    if (e >= E + N) return;
    int s, d;
    if (e < E) { s = ei[e]; d = ei[E + e]; } else { s = e - E; d = s; }
    csr[rs[d] + rank[e]] = s;      // fire-and-forget random store
}

// ---------------- layer-1 gather: 16 lanes/dst, 8 bf16 ch/lane (uint4 loads),
// 16-edge chunks fully unrolled. Output packed bf16 (feeds gemm2 MFMA).
__global__ __launch_bounds__(256) void gather1_k(
    const int* __restrict__ rs, const int* __restrict__ csr,
    const float* __restrict__ as_, const float* __restrict__ ad_,
    const uint4* __restrict__ h, const float* __restrict__ b,
    ushort* __restrict__ o, int N) {
    const int jj = threadIdx.x & 31;
    const int l16 = jj & 15;
    const int sub = jj & 16;             // 16-lane subgroup base in 32-window
    const int d = blockIdx.x * 16 + (threadIdx.x >> 5) * 2 + (jj >> 4);
    if (d >= N) return;
    const int hl = l16 >> 2;             // my head
    const int sl = l16 & 3;              // my slot base
    const int beg = rs[d], end = rs[d + 1];
    const float adv = ad_[d * 4 + hl];

    float acc[8];
#pragma unroll
    for (int i = 0; i < 8; i++) acc[i] = 0.f;
    float den = 0.f;

    int j0 = beg;
    for (; j0 + 16 <= end; j0 += 16) {
        int sv0 = csr[j0 + sl];
        int sv1 = csr[j0 + sl + 4];
        int sv2 = csr[j0 + sl + 8];
        int sv3 = csr[j0 + sl + 12];
        float ex0 = __expf(fminf(lrelu(as_[sv0 * 4 + hl] + adv), 80.f));
        float ex1 = __expf(fminf(lrelu(as_[sv1 * 4 + hl] + adv), 80.f));
        float ex2 = __expf(fminf(lrelu(as_[sv2 * 4 + hl] + adv), 80.f));
        float ex3 = __expf(fminf(lrelu(as_[sv3 * 4 + hl] + adv), 80.f));
        den += ex0 + ex1 + ex2 + ex3;
#pragma unroll
        for (int k = 0; k < 4; k++) {
            float exk = (k == 0) ? ex0 : (k == 1) ? ex1 : (k == 2) ? ex2 : ex3;
            int   svk = (k == 0) ? sv0 : (k == 1) ? sv1 : (k == 2) ? sv2 : sv3;
#pragma unroll
            for (int q = 0; q < 4; q++) {
                int src = sub + (l16 & 12) + q;
                float a = __shfl(exk, src, 32);
                int   s = __shfl(svk, src, 32);
                uint4 hv = h[(size_t)s * 16 + l16];
                bf16x8_fma(hv, a, acc);
            }
        }
    }
    int r = end - j0;
    if (r > 0) {
        float exs[4] = {0.f, 0.f, 0.f, 0.f};
        int   svs[4] = {0, 0, 0, 0};
#pragma unroll
        for (int k = 0; k < 4; k++) {
            int slot = sl + 4 * k;
            if (slot < r) {
                int s = csr[j0 + slot];
                svs[k] = s;
                exs[k] = __expf(fminf(lrelu(as_[s * 4 + hl] + adv), 80.f));
                den += exs[k];
            }
        }
        for (int e = 0; e < r; e++) {
            int k = e >> 2, q = e & 3;
            float exk = (k == 0) ? exs[0] : (k == 1) ? exs[1] : (k == 2) ? exs[2] : exs[3];
            int   svk = (k == 0) ? svs[0] : (k == 1) ? svs[1] : (k == 2) ? svs[2] : svs[3];
            int src = sub + (l16 & 12) + q;
            float a = __shfl(exk, src, 32);
            int   s = __shfl(svk, src, 32);
            uint4 hv = h[(size_t)s * 16 + l16];
            bf16x8_fma(hv, a, acc);
        }
    }
    den += __shfl_xor(den, 1, 32);
    den += __shfl_xor(den, 2, 32);
    const float rcp = 1.f / (den + 1e-16f);
    float4 b0 = *(const float4*)&b[l16 * 8];
    float4 b1 = *(const float4*)&b[l16 * 8 + 4];
    float v0 = fmaxf(acc[0] * rcp + b0.x, 0.f);
    float v1 = fmaxf(acc[1] * rcp + b0.y, 0.f);
    float v2 = fmaxf(acc[2] * rcp + b0.z, 0.f);
    float v3 = fmaxf(acc[3] * rcp + b0.w, 0.f);
    float v4 = fmaxf(acc[4] * rcp + b1.x, 0.f);
    float v5 = fmaxf(acc[5] * rcp + b1.y, 0.f);
    float v6 = fmaxf(acc[6] * rcp + b1.z, 0.f);
    float v7 = fmaxf(acc[7] * rcp + b1.w, 0.f);
    uint4 pk;
    pk.x = f2bf(v0) | (f2bf(v1) << 16);
    pk.y = f2bf(v2) | (f2bf(v3) << 16);
    pk.z = f2bf(v4) | (f2bf(v5) << 16);
    pk.w = f2bf(v6) | (f2bf(v7) << 16);
    ((uint4*)o)[(size_t)d * 16 + l16] = pk;
}

// ---------------- layer-2 gather: 4 lanes/dst, 8 bf16 ch/lane, 16-edge chunks.
__global__ __launch_bounds__(256) void gather2_k(
    const int* __restrict__ rs, const int* __restrict__ csr,
    const float* __restrict__ as_, const float* __restrict__ ad_,
    const uint4* __restrict__ h, const float* __restrict__ b,
    float* __restrict__ o, int N) {
    const int jj = threadIdx.x & 31;
    const int l4 = jj & 3;
    const int sub = jj & 28;             // 4-lane subgroup base
    const int d = blockIdx.x * 64 + (threadIdx.x >> 5) * 8 + (jj >> 2);
    if (d >= N) return;
    const int beg = rs[d], end = rs[d + 1];
    const float adv = ad_[d];

    float acc[8];
#pragma unroll
    for (int i = 0; i < 8; i++) acc[i] = 0.f;
    float den = 0.f;

    int j0 = beg;
    for (; j0 + 16 <= end; j0 += 16) {
        int sv0 = csr[j0 + l4];
        int sv1 = csr[j0 + l4 + 4];
        int sv2 = csr[j0 + l4 + 8];
        int sv3 = csr[j0 + l4 + 12];
        float ex0 = __expf(fminf(lrelu(as_[sv0] + adv), 80.f));
        float ex1 = __expf(fminf(lrelu(as_[sv1] + adv), 80.f));
        float ex2 = __expf(fminf(lrelu(as_[sv2] + adv), 80.f));
        float ex3 = __expf(fminf(lrelu(as_[sv3] + adv), 80.f));
        den += ex0 + ex1 + ex2 + ex3;
#pragma unroll
        for (int k = 0; k < 4; k++) {
            float exk = (k == 0) ? ex0 : (k == 1) ? ex1 : (k == 2) ? ex2 : ex3;
            int   svk = (k == 0) ? sv0 : (k == 1) ? sv1 : (k == 2) ? sv2 : sv3;
#pragma unroll
            for (int q = 0; q < 4; q++) {
                int src = sub + q;
                float a = __shfl(exk, src, 32);
                int   s = __shfl(svk, src, 32);
                uint4 hv = h[(size_t)s * 4 + l4];
                bf16x8_fma(hv, a, acc);
            }
        }
    }
    int r = end - j0;
    if (r > 0) {
        float exs[4] = {0.f, 0.f, 0.f, 0.f};
        int   svs[4] = {0, 0, 0, 0};
#pragma unroll
        for (int k = 0; k < 4; k++) {
            int slot = l4 + 4 * k;
            if (slot < r) {
                int s = csr[j0 + slot];
                svs[k] = s;
                exs[k] = __expf(fminf(lrelu(as_[s] + adv), 80.f));
                den += exs[k];
            }
        }
        for (int e = 0; e < r; e++) {
            int k = e >> 2, q = e & 3;
            float exk = (k == 0) ? exs[0] : (k == 1) ? exs[1] : (k == 2) ? exs[2] : exs[3];
            int   svk = (k == 0) ? svs[0] : (k == 1) ? svs[1] : (k == 2) ? svs[2] : svs[3];
            int src = sub + q;
            float a = __shfl(exk, src, 32);
            int   s = __shfl(svk, src, 32);
            uint4 hv = h[(size_t)s * 4 + l4];
            bf16x8_fma(hv, a, acc);
        }
    }
    den += __shfl_xor(den, 1, 32);
    den += __shfl_xor(den, 2, 32);
    const float rcp = 1.f / (den + 1e-16f);
    float4 b0 = *(const float4*)&b[l4 * 8];
    float4 b1 = *(const float4*)&b[l4 * 8 + 4];
    float4 o0, o1v;
    o0.x  = acc[0] * rcp + b0.x;
    o0.y  = acc[1] * rcp + b0.y;
    o0.z  = acc[2] * rcp + b0.z;
    o0.w  = acc[3] * rcp + b0.w;
    o1v.x = acc[4] * rcp + b1.x;
    o1v.y = acc[5] * rcp + b1.y;
    o1v.z = acc[6] * rcp + b1.z;
    o1v.w = acc[7] * rcp + b1.w;
    *(float4*)&o[(size_t)d * 32 + l4 * 8]     = o0;
    *(float4*)&o[(size_t)d * 32 + l4 * 8 + 4] = o1v;
}

extern "C" void kernel_launch(void* const* d_in, const int* in_sizes, int n_in,
                              void* d_out, int out_size, void* d_ws, size_t ws_size,
                              hipStream_t stream) {
    const float* x    = (const float*)d_in[0];
    const int*   ei   = (const int*)d_in[1];
    const float* W1   = (const float*)d_in[2];
    const float* as1v = (const float*)d_in[3];
    const float* ad1v = (const float*)d_in[4];
    const float* b1   = (const float*)d_in[5];
    const float* W2   = (const float*)d_in[6];
    const float* as2v = (const float*)d_in[7];
    const float* ad2v = (const float*)d_in[8];
    const float* b2   = (const float*)d_in[9];
    float* out = (float*)d_out;

    const int N = in_sizes[0] / 128;
    const int E = in_sizes[1] / 2;
    const int EN = E + N;
    const int B = (N + 255) / 256;   // scan chunks (must be <= 1024)

    // workspace layout
    char* base = (char*)d_ws;
    size_t o = 0;
    auto alloc = [&](size_t bytes) { void* p = base + o; o += (bytes + 255) & ~(size_t)255; return p; };
    ushort* xb   = (ushort*)alloc((size_t)N * 128 * 2);
    ushort* w1t  = (ushort*)alloc((size_t)128 * 128 * 2);
    ushort* w2t  = (ushort*)alloc((size_t)32 * 128 * 2);
    ushort* h1   = (ushort*)alloc((size_t)N * 128 * 2);
    ushort* h2   = (ushort*)alloc((size_t)N * 32 * 2);
    ushort* o1   = (ushort*)alloc((size_t)N * 128 * 2);
    float*  as1  = (float*)alloc((size_t)N * 4 * 4);
    float*  ad1  = (float*)alloc((size_t)N * 4 * 4);
    float*  as2  = (float*)alloc((size_t)N * 4);
    float*  ad2  = (float*)alloc((size_t)N * 4);
    int*    deg  = (int*)alloc((size_t)N * 4);
    int*    tmp  = (int*)alloc((size_t)N * 4);
    int*    part = (int*)alloc((size_t)1024 * 4);
    int*    rs   = (int*)alloc((size_t)(N + 1) * 4);
    int*    rank = (int*)alloc((size_t)EN * 4);
    int*    csr  = (int*)alloc((size_t)EN * 4);

    hipMemsetAsync(deg, 0, (size_t)N * 4, stream);

    const int nbE = (EN + 255) / 256;
    const int nbN = (N + 255) / 256;
    const int nbG = (N + 63) / 64;
    const long long n8 = (long long)N * 128 / 8;

    // ---- casts + layer-1 GEMM (MFMA) + CSR build
    cast_x_k<<<(unsigned)((n8 + 255) / 256), 256, 0, stream>>>(x, xb, n8);
    cast_w_k<<<64, 256, 0, stream>>>(W1, W2, w1t, w2t);
    gemm1_mfma<<<nbG, 256, 0, stream>>>(xb, w1t, as1v, ad1v, h1, as1, ad1, N);
    hist_rank_k<<<nbE, 256, 0, stream>>>(ei, E, N, deg, rank);
    scan1_k<<<nbN, 256, 0, stream>>>(deg, tmp, part, N);
    scan2_k<<<1, 1024, 0, stream>>>(part, B);
    scan3_k<<<nbN, 256, 0, stream>>>(tmp, part, rs, N);
    scatter_k<<<nbE, 256, 0, stream>>>(ei, rank, rs, E, N, csr);

    // ---- layer 1 edge softmax + aggregate + bias + relu -> o1 (bf16)
    gather1_k<<<(N + 15) / 16, 256, 0, stream>>>(rs, csr, as1, ad1, (const uint4*)h1, b1, o1, N);

    // ---- layer 2
    gemm2_mfma<<<nbG, 256, 0, stream>>>(o1, w2t, as2v, ad2v, h2, as2, ad2, N);
    gather2_k<<<(N + 63) / 64, 256, 0, stream>>>(rs, csr, as2, ad2, (const uint4*)h2, b2, out, N);
}